// Round 1
// baseline (338.510 us; speedup 1.0000x reference)
//
#include <hip/hip_runtime.h>
#include <hip/hip_bf16.h>
#include <hip/hip_fp16.h>

// GCN: out = softmax( GCNConv2( relu( GCNConv1(x) ) ) )
// GCNConv(x) = D^-1/2 (A+I) D^-1/2 (x W) + b
//
// Round 12:
//  (a) gather_relu_f16 col-split by XCD parity: block parity c = blockIdx&1
//      selects which 128 B half of the 256 B h1h row this block gathers.
//      With round-robin block->XCD dispatch (XCD = blockIdx % 8), even XCDs
//      only ever touch half 0, odd XCDs half 1 -> per-XCD L2 working set
//      drops 25.6 MB -> 12.8 MB, and per-XCD compulsory fabric traffic
//      halves (FETCH 193 MB -> ~115-135 MB predicted). Each wave still owns
//      one dst node but gathers TWO edges per load instruction (lanes 0-31 =
//      edge 2p, lanes 32-63 = edge 2p+1, 128 B half-row each => 256 B/instr),
//      combined with one __shfl_xor(...,32) at the end.
//  (b) rest unchanged from Round 11 (MFMA GEMMs, fp16 intermediates,
//      two-level CSR partition).
// Requires N <= 2^17. N = 100000 here.

#define K_DIM 128
#define PART_VE 16
#define PART_CHUNK 4096   // 256 threads * 16 edges
#define NB_MAX 128        // bucket array size (N <= 128*1024)
#define LDA 136           // LDS row stride in halfs (128 + 8 pad)

typedef _Float16 half8 __attribute__((ext_vector_type(8)));
typedef float floatx4 __attribute__((ext_vector_type(4)));

__global__ __launch_bounds__(128) void zero_small(int* p) {
    p[threadIdx.x] = 0;
}

// Per-bucket edge counts (bucket = dst >> 10).
__global__ __launch_bounds__(256) void hist_buckets(const int* __restrict__ dst, int E,
                                                    int* __restrict__ bucket_count) {
    __shared__ int h[NB_MAX];
    const int t = threadIdx.x;
    if (t < NB_MAX) h[t] = 0;
    __syncthreads();
    const int e0 = blockIdx.x * PART_CHUNK;
    #pragma unroll
    for (int q = 0; q < PART_VE; ++q) {
        const int e = e0 + q * 256 + t;
        if (e < E) atomicAdd(&h[dst[e] >> 10], 1);
    }
    __syncthreads();
    if (t < NB_MAX && h[t]) atomicAdd(&bucket_count[t], h[t]);
}

// Single-wave exclusive scan of the 128 bucket counts (lane owns 2 buckets).
__global__ __launch_bounds__(64) void scan_buckets(const int* __restrict__ bucket_count,
                                                   int* __restrict__ bucket_base,
                                                   int* __restrict__ bucket_cursor,
                                                   int* __restrict__ rowptr, int N, int E) {
    const int t = threadIdx.x;
    const int v0 = bucket_count[2 * t], v1 = bucket_count[2 * t + 1];
    const int tsum = v0 + v1;
    int inc = tsum;
    #pragma unroll
    for (int off = 1; off < 64; off <<= 1) {
        int u = __shfl_up(inc, off, 64);
        if (t >= off) inc += u;
    }
    const int excl = inc - tsum;
    bucket_base[2 * t] = excl;
    bucket_base[2 * t + 1] = excl + v0;
    bucket_cursor[2 * t] = excl;
    bucket_cursor[2 * t + 1] = excl + v0;
    if (t == 63) bucket_base[NB_MAX] = inc;   // == E
    if (t == 0) rowptr[N] = E;
}

// Partition edges into per-bucket contiguous regions with coalesced writes.
// Packed record: (d & 1023) << 17 | src.
__global__ __launch_bounds__(256) void partition_edges(
    const int* __restrict__ ei, int E,
    int* __restrict__ bucket_cursor, int* __restrict__ packed_out)
{
    __shared__ int stage[PART_CHUNK];
    __shared__ unsigned char bstage[PART_CHUNK];
    __shared__ int hist[NB_MAX], lbase[NB_MAX], gbase[NB_MAX], lcur[NB_MAX];
    const int t = threadIdx.x;
    const int e0 = blockIdx.x * PART_CHUNK;
    if (t < NB_MAX) hist[t] = 0;
    __syncthreads();

    int pk[PART_VE], bk[PART_VE];
    #pragma unroll
    for (int q = 0; q < PART_VE; ++q) {
        const int e = e0 + q * 256 + t;
        bk[q] = -1;
        if (e < E) {
            const int s = ei[e];
            const int d = ei[E + e];
            bk[q] = d >> 10;
            pk[q] = ((d & 1023) << 17) | s;
            atomicAdd(&hist[bk[q]], 1);
        }
    }
    __syncthreads();

    if (t < 64) {
        const int v0 = hist[2 * t], v1 = hist[2 * t + 1];
        const int tsum = v0 + v1;
        int inc = tsum;
        #pragma unroll
        for (int off = 1; off < 64; off <<= 1) {
            int u = __shfl_up(inc, off, 64);
            if (t >= off) inc += u;
        }
        const int excl = inc - tsum;
        lbase[2 * t] = excl;        lbase[2 * t + 1] = excl + v0;
        lcur[2 * t]  = excl;        lcur[2 * t + 1]  = excl + v0;
        gbase[2 * t]     = v0 ? atomicAdd(&bucket_cursor[2 * t], v0) : 0;
        gbase[2 * t + 1] = v1 ? atomicAdd(&bucket_cursor[2 * t + 1], v1) : 0;
    }
    __syncthreads();

    #pragma unroll
    for (int q = 0; q < PART_VE; ++q) {
        if (bk[q] >= 0) {
            const int p = atomicAdd(&lcur[bk[q]], 1);
            stage[p]  = pk[q];
            bstage[p] = (unsigned char)bk[q];
        }
    }
    __syncthreads();

    const int total = (E - e0 < PART_CHUNK) ? (E - e0) : PART_CHUNK;
    for (int i = t; i < total; i += 256) {
        const int b = bstage[i];
        packed_out[gbase[b] + (i - lbase[b])] = stage[i];
    }
}

// One block per 1024-node bucket: local histogram -> local scan -> rowptr/norm
// -> LDS-cursor scatter into this bucket's contiguous csr segment.
__global__ __launch_bounds__(1024) void build_csr(
    const int* __restrict__ packed, const int* __restrict__ bucket_base,
    int N, int* __restrict__ rowptr, float* __restrict__ normv,
    int* __restrict__ csr)
{
    __shared__ int ldeg[1024];
    __shared__ int lrow[1024];
    __shared__ int wtot[16];
    const int b = blockIdx.x;
    const int node0 = b << 10;
    const int t = threadIdx.x;
    const int jb = bucket_base[b], je = bucket_base[b + 1];

    ldeg[t] = 0;
    __syncthreads();
    for (int j = jb + t; j < je; j += 1024)
        atomicAdd(&ldeg[packed[j] >> 17], 1);
    __syncthreads();

    const int lane = t & 63, wid = t >> 6;
    const int v = ldeg[t];
    int inc = v;
    #pragma unroll
    for (int off = 1; off < 64; off <<= 1) {
        int u = __shfl_up(inc, off, 64);
        if (lane >= off) inc += u;
    }
    if (lane == 63) wtot[wid] = inc;
    __syncthreads();
    int woff = 0;
    for (int w = 0; w < wid; ++w) woff += wtot[w];
    const int excl = woff + inc - v;
    lrow[t] = excl;
    __syncthreads();

    const int nloc = (N - node0 < 1024) ? (N - node0) : 1024;
    if (t < nloc) {
        rowptr[node0 + t] = jb + excl;
        normv[node0 + t] = rsqrtf((float)(v + 1));   // +1 self-loop
    }
    __syncthreads();

    for (int j = jb + t; j < je; j += 1024) {
        const int pv = packed[j];
        const int slot = jb + atomicAdd(&lrow[pv >> 17], 1);
        csr[slot] = pv & 0x1FFFF;
    }
}

// Transpose-convert weights for MFMA B-operand: W1h[n][k] = (half)W1[k][n],
// W2h[n][k] = (half)W2[k][n]. 16384 + 8192 elems; one tiny kernel.
__global__ __launch_bounds__(256) void prep_weights(
    const float* __restrict__ W1, const float* __restrict__ W2,
    __half* __restrict__ W1h, __half* __restrict__ W2h)
{
    const int idx = blockIdx.x * 256 + threadIdx.x;
    if (idx < 128 * 128) {
        const int n = idx >> 7, k = idx & 127;
        W1h[idx] = __float2half(W1[k * 128 + n]);
    }
    const int idx2 = idx - 128 * 128;
    if (idx2 >= 0 && idx2 < 64 * 128) {
        const int n = idx2 >> 7, k = idx2 & 127;
        W2h[idx2] = __float2half(W2[k * 64 + n]);
    }
}

// Layer-1 MFMA GEMM: H'[row,0..127] = norm[row]*(x[row,:]@W1), fp16 out.
// Split-A (x = hi + lo) so only W-fp16 quantization enters the result.
// 256 thr = 4 waves; wave w owns rows w*16..+15, all 8 col-tiles.
__global__ __launch_bounds__(256) void gemm128_mfma(
    const float* __restrict__ A, const __half* __restrict__ Wh,  // [n][k]
    const float* __restrict__ norm, __half* __restrict__ Hout, int nrows)
{
    __shared__ _Float16 Ah[64 * LDA];
    __shared__ _Float16 Al[64 * LDA];
    __shared__ _Float16 Bh[128 * LDA];
    const int t = threadIdx.x;
    const int row0 = blockIdx.x * 64;

    {   // stage A split hi/lo: thread t -> row t>>2, 32-col segment (t&3)*32
        const int r = t >> 2;
        const int seg = (t & 3) * 32;
        int grow = row0 + r;
        if (grow > nrows - 1) grow = nrows - 1;
        const float* src = &A[(size_t)grow * K_DIM + seg];
        _Float16 hi[32], lo[32];
        #pragma unroll
        for (int i = 0; i < 8; ++i) {
            float4 v = *(const float4*)&src[i * 4];
            const float vf[4] = {v.x, v.y, v.z, v.w};
            #pragma unroll
            for (int j = 0; j < 4; ++j) {
                _Float16 h = (_Float16)vf[j];
                hi[i * 4 + j] = h;
                lo[i * 4 + j] = (_Float16)(vf[j] - (float)h);
            }
        }
        #pragma unroll
        for (int c = 0; c < 4; ++c) {
            *(half8*)&Ah[r * LDA + seg + c * 8] = *(half8*)&hi[c * 8];
            *(half8*)&Al[r * LDA + seg + c * 8] = *(half8*)&lo[c * 8];
        }
    }
    {   // stage B: 128x128 halfs = 2048 b128-chunks, 8 per thread
        const _Float16* wf = (const _Float16*)Wh;
        #pragma unroll
        for (int i = 0; i < 8; ++i) {
            const int id = i * 256 + t;
            const int n = id >> 4, kc = id & 15;
            *(half8*)&Bh[n * LDA + kc * 8] = *(const half8*)&wf[n * 128 + kc * 8];
        }
    }
    __syncthreads();

    const int lane = t & 63, wave = t >> 6;
    const int m = lane & 15, quad = lane >> 4;
    const int arow = wave * 16 + m;

    floatx4 acc[8];
    #pragma unroll
    for (int nt = 0; nt < 8; ++nt) acc[nt] = (floatx4){0.f, 0.f, 0.f, 0.f};

    #pragma unroll
    for (int k0 = 0; k0 < 128; k0 += 32) {
        half8 ah = *(const half8*)&Ah[arow * LDA + k0 + quad * 8];
        half8 al = *(const half8*)&Al[arow * LDA + k0 + quad * 8];
        #pragma unroll
        for (int nt = 0; nt < 8; ++nt) {
            half8 b = *(const half8*)&Bh[(nt * 16 + m) * LDA + k0 + quad * 8];
            acc[nt] = __builtin_amdgcn_mfma_f32_16x16x32_f16(ah, b, acc[nt], 0, 0, 0);
            acc[nt] = __builtin_amdgcn_mfma_f32_16x16x32_f16(al, b, acc[nt], 0, 0, 0);
        }
    }

    // D: row = quad*4 + reg, col = nt*16 + m
    #pragma unroll
    for (int reg = 0; reg < 4; ++reg) {
        const int row = row0 + wave * 16 + quad * 4 + reg;
        if (row < nrows) {
            const float nr = norm[row];
            #pragma unroll
            for (int nt = 0; nt < 8; ++nt)
                Hout[(size_t)row * 128 + nt * 16 + m] = __float2half(acc[nt][reg] * nr);
        }
    }
}

// Layer-2 MFMA GEMM: H'[row,0..63] = norm[row]*(agg1h[row,:]@W2), fp16 out.
// A input is fp16 (exact-as-stored); W2h fp16 [n][k].
__global__ __launch_bounds__(256) void gemm64_mfma(
    const __half* __restrict__ A, const __half* __restrict__ Wh,
    const float* __restrict__ norm, __half* __restrict__ Hout, int nrows)
{
    __shared__ _Float16 Ah[64 * LDA];
    __shared__ _Float16 Bh[64 * LDA];
    const int t = threadIdx.x;
    const int row0 = blockIdx.x * 64;
    const _Float16* af = (const _Float16*)A;
    const _Float16* wf = (const _Float16*)Wh;

    {   // stage A: 64x128 halfs = 1024 chunks, 4 per thread
        #pragma unroll
        for (int i = 0; i < 4; ++i) {
            const int id = i * 256 + t;
            const int r = id >> 4, kc = id & 15;
            int grow = row0 + r;
            if (grow > nrows - 1) grow = nrows - 1;
            *(half8*)&Ah[r * LDA + kc * 8] = *(const half8*)&af[(size_t)grow * 128 + kc * 8];
        }
    }
    {   // stage B: 64x128 halfs = 1024 chunks, 4 per thread
        #pragma unroll
        for (int i = 0; i < 4; ++i) {
            const int id = i * 256 + t;
            const int n = id >> 4, kc = id & 15;
            *(half8*)&Bh[n * LDA + kc * 8] = *(const half8*)&wf[n * 128 + kc * 8];
        }
    }
    __syncthreads();

    const int lane = t & 63, wave = t >> 6;
    const int m = lane & 15, quad = lane >> 4;
    const int arow = wave * 16 + m;

    floatx4 acc[4];
    #pragma unroll
    for (int nt = 0; nt < 4; ++nt) acc[nt] = (floatx4){0.f, 0.f, 0.f, 0.f};

    #pragma unroll
    for (int k0 = 0; k0 < 128; k0 += 32) {
        half8 ah = *(const half8*)&Ah[arow * LDA + k0 + quad * 8];
        #pragma unroll
        for (int nt = 0; nt < 4; ++nt) {
            half8 b = *(const half8*)&Bh[(nt * 16 + m) * LDA + k0 + quad * 8];
            acc[nt] = __builtin_amdgcn_mfma_f32_16x16x32_f16(ah, b, acc[nt], 0, 0, 0);
        }
    }

    #pragma unroll
    for (int reg = 0; reg < 4; ++reg) {
        const int row = row0 + wave * 16 + quad * 4 + reg;
        if (row < nrows) {
            const float nr = norm[row];
            #pragma unroll
            for (int nt = 0; nt < 4; ++nt)
                Hout[(size_t)row * 64 + nt * 16 + m] = __float2half(acc[nt][reg] * nr);
        }
    }
}

// Layer-1 aggregation, XCD-col-split: block parity c = blockIdx&1 picks which
// 128 B half of each 256 B h' row this block gathers (round-robin dispatch ->
// even XCDs only touch half 0, odd XCDs half 1 -> per-XCD L2 working set
// 12.8 MB instead of 25.6 MB). One wave per dst node; lanes 0-31 gather edge
// 2p, lanes 32-63 edge 2p+1 (one 256 B load instr covers 2 half-rows);
// halves combined with __shfl_xor(...,32) at the end.
//   agg[d, c*64 .. c*64+63] = relu( nd * (sum_e h'[s_e,half] + h'[d,half]) + bias )
__global__ __launch_bounds__(256) void gather_relu_f16(
    const int* __restrict__ rowptr, const int* __restrict__ csr,
    const float* __restrict__ norm, const __half* __restrict__ h,
    const float* __restrict__ bias, __half* __restrict__ agg, int n)
{
    const int t = threadIdx.x;
    const int B = blockIdx.x;
    const int c = B & 1;                                   // column half (XCD parity)
    const int d = __builtin_amdgcn_readfirstlane((B >> 1) * 4 + (t >> 6));
    if (d >= n) return;
    const int lane = t & 63;
    const int half = lane >> 5;                            // which edge of a pair
    const int cl = (lane & 31) + c * 32;                   // half2 col index (0..63)
    const __half2* hp = (const __half2*)h;                 // row stride 64 half2 (256 B)

    const int jb = rowptr[d], je = rowptr[d + 1];
    float ax[4] = {}, ay[4] = {};                          // pair accumulators
    float tx = 0.f, ty = 0.f;                              // tail+self (lanes<32 only)
    int j = jb;
    if (j + 8 <= je) {
        int s[8];
        #pragma unroll
        for (int q = 0; q < 8; ++q) s[q] = csr[j + q];
        for (; j + 16 <= je; j += 8) {
            int sn[8];
            #pragma unroll
            for (int q = 0; q < 8; ++q) sn[q] = csr[j + 8 + q];
            #pragma unroll
            for (int p = 0; p < 4; ++p) {
                const float2 v = __half22float2(hp[(size_t)s[2 * p + half] * 64 + cl]);
                ax[p] += v.x; ay[p] += v.y;
            }
            #pragma unroll
            for (int q = 0; q < 8; ++q) s[q] = sn[q];
        }
        #pragma unroll
        for (int p = 0; p < 4; ++p) {
            const float2 v = __half22float2(hp[(size_t)s[2 * p + half] * 64 + cl]);
            ax[p] += v.x; ay[p] += v.y;
        }
        j += 8;
    }
    for (; j + 2 <= je; j += 2) {                          // pair tail
        const float2 v = __half22float2(hp[(size_t)csr[j + half] * 64 + cl]);
        ax[0] += v.x; ay[0] += v.y;
    }
    if (half == 0) {
        if (j < je) {                                      // odd last edge
            const float2 v = __half22float2(hp[(size_t)csr[j] * 64 + cl]);
            tx += v.x; ty += v.y;
        }
        const float2 sv = __half22float2(hp[(size_t)d * 64 + cl]);  // self (premult)
        tx += sv.x; ty += sv.y;
    }

    float sx = ((ax[0] + ax[1]) + (ax[2] + ax[3])) + tx;
    float sy = ((ay[0] + ay[1]) + (ay[2] + ay[3])) + ty;
    sx += __shfl_xor(sx, 32, 64);
    sy += __shfl_xor(sy, 32, 64);

    const float nd = norm[d];
    const float ox = fmaxf(fmaf(nd, sx, bias[2 * cl]), 0.f);
    const float oy = fmaxf(fmaf(nd, sy, bias[2 * cl + 1]), 0.f);
    if (half == 0)
        ((__half2*)agg)[(size_t)d * 64 + cl] = __floats2half2_rn(ox, oy);
}

// Layer-2 aggregation + row softmax (scalar-path); h' fp16, 64 cols = 64 lanes.
__global__ __launch_bounds__(256) void gather_softmax(
    const int* __restrict__ rowptr, const int* __restrict__ csr,
    const float* __restrict__ norm, const __half* __restrict__ h,
    const float* __restrict__ bias, float* __restrict__ out, int n)
{
    const int lane = threadIdx.x & 63;
    const int d = __builtin_amdgcn_readfirstlane(blockIdx.x * 4 + (threadIdx.x >> 6));
    if (d >= n) return;

    const int jb = rowptr[d], je = rowptr[d + 1];
    float acc[8] = {};
    int j = jb;
    if (j + 8 <= je) {
        int s[8];
        #pragma unroll
        for (int q = 0; q < 8; ++q) s[q] = csr[j + q];
        for (; j + 16 <= je; j += 8) {
            int sn[8];
            #pragma unroll
            for (int q = 0; q < 8; ++q) sn[q] = csr[j + 8 + q];
            #pragma unroll
            for (int q = 0; q < 8; ++q)
                acc[q] += __half2float(h[(size_t)s[q] * 64 + lane]);
            #pragma unroll
            for (int q = 0; q < 8; ++q) s[q] = sn[q];
        }
        #pragma unroll
        for (int q = 0; q < 8; ++q)
            acc[q] += __half2float(h[(size_t)s[q] * 64 + lane]);
        j += 8;
    }
    for (; j < je; ++j)
        acc[0] += __half2float(h[(size_t)csr[j] * 64 + lane]);

    const float nd = norm[d];
    float tot = ((acc[0] + acc[1]) + (acc[2] + acc[3])) +
                ((acc[4] + acc[5]) + (acc[6] + acc[7])) +
                __half2float(h[(size_t)d * 64 + lane]);
    float a = fmaf(nd, tot, bias[lane]);
    float m = a;
    #pragma unroll
    for (int off = 32; off; off >>= 1) m = fmaxf(m, __shfl_xor(m, off, 64));
    float ex = expf(a - m);
    float ssum = ex;
    #pragma unroll
    for (int off = 32; off; off >>= 1) ssum += __shfl_xor(ssum, off, 64);
    out[(size_t)d * 64 + lane] = ex / ssum;
}

extern "C" void kernel_launch(void* const* d_in, const int* in_sizes, int n_in,
                              void* d_out, int out_size, void* d_ws, size_t ws_size,
                              hipStream_t stream) {
    const float* x  = (const float*)d_in[0];
    const int*   ei = (const int*)d_in[1];
    const float* W1 = (const float*)d_in[2];
    const float* b1 = (const float*)d_in[3];
    const float* W2 = (const float*)d_in[4];
    const float* b2 = (const float*)d_in[5];
    float* out = (float*)d_out;

    const int N = in_sizes[0] / K_DIM;     // 100000 (<= 2^17 required)
    const int E = in_sizes[1] / 2;         // 1600000
    const int NBUCK = (N + 1023) >> 10;    // 98 buckets of 1024 nodes

    // Workspace layout (peak ~65 MB)
    size_t o = 0;
    char* base = (char*)d_ws;
    auto alloc = [&](size_t elems) {       // elems in 4-byte units
        void* p = base + o;
        o += (elems * 4 + 1023) & ~(size_t)1023;
        return p;
    };
    int*    bcount = (int*)   alloc(NB_MAX);
    int*    bbase  = (int*)   alloc(NB_MAX + 1);
    int*    bcur   = (int*)   alloc(NB_MAX);
    int*    rowptr = (int*)   alloc(N + 1);
    float*  norm   = (float*) alloc(N);
    int*    packed = (int*)   alloc(E);
    int*    csr    = (int*)   alloc(E);
    __half* W1h    = (__half*)alloc(128 * 128 / 2);
    __half* W2h    = (__half*)alloc(64 * 128 / 2);
    void*   bufA   = alloc((size_t)N * 64);          // h1h fp16 [Nx128] / h2h fp16 [Nx64]
    __half* agg1h  = (__half*)alloc((size_t)N * 64); // fp16 [Nx128]

    __half* h1h = (__half*)bufA;
    __half* h2h = (__half*)bufA;

    const int nb_c = (E + PART_CHUNK - 1) / PART_CHUNK;   // partition chunks
    const int nb_g = (N + 3) / 4;
    const int nb_g2 = 2 * nb_g;            // col-split gather: 2 blocks per dst group
    const int nb_m = (N + 63) / 64;

    // ---- CSR build (two-level partition) + weight prep ----
    zero_small<<<1, NB_MAX, 0, stream>>>(bcount);
    prep_weights<<<96, 256, 0, stream>>>(W1, W2, W1h, W2h);
    hist_buckets<<<nb_c, 256, 0, stream>>>(ei + E, E, bcount);
    scan_buckets<<<1, 64, 0, stream>>>(bcount, bbase, bcur, rowptr, N, E);
    partition_edges<<<nb_c, 256, 0, stream>>>(ei, E, bcur, packed);
    build_csr<<<NBUCK, 1024, 0, stream>>>(packed, bbase, N, rowptr, norm, csr);

    // ---- Layer 1: h1' = norm .* (x@W1), fp16 [N x 128], MFMA split-A ----
    gemm128_mfma<<<nb_m, 256, 0, stream>>>(x, W1h, norm, h1h, N);
    gather_relu_f16<<<nb_g2, 256, 0, stream>>>(rowptr, csr, norm, h1h, b1, agg1h, N);

    // ---- Layer 2: h2' = norm .* (agg1@W2), fp16 [N x 64], MFMA ----
    gemm64_mfma<<<nb_m, 256, 0, stream>>>(agg1h, W2h, norm, h2h, N);
    gather_softmax<<<nb_g, 256, 0, stream>>>(rowptr, csr, norm, h2h, b2, out, N);
}

// Round 2
// 327.260 us; speedup vs baseline: 1.0344x; 1.0344x over previous
//
#include <hip/hip_runtime.h>
#include <hip/hip_bf16.h>
#include <hip/hip_fp16.h>

// GCN: out = softmax( GCNConv2( relu( GCNConv1(x) ) ) )
// GCNConv(x) = D^-1/2 (A+I) D^-1/2 (x W) + b
//
// Round 13:
//  (a) REVERT round-12 col-split gather (105 us, BW fell to 2 TB/s: halved
//      MLP, and 12.8 MB half-table still misses 4 MB per-XCD L2). Gather
//      inner loop restored to the proven R11 form (62 us, 3.6 TB/s).
//  (b) FUSE gemm64 into the gather: block owns 64 dst rows (4 waves x 16
//      sequential dsts), relu'd aggregation tile goes to LDS, then the
//      proven gemm64 MFMA body (W2 LDS-staged) produces h2' directly.
//      Saves 25.6 MB agg1h write + 25.6 MB re-read + one dispatch.
// Requires N <= 2^17. N = 100000 here.

#define K_DIM 128
#define PART_VE 16
#define PART_CHUNK 4096   // 256 threads * 16 edges
#define NB_MAX 128        // bucket array size (N <= 128*1024)
#define LDA 136           // LDS row stride in halfs (128 + 8 pad)

typedef _Float16 half8 __attribute__((ext_vector_type(8)));
typedef float floatx4 __attribute__((ext_vector_type(4)));

__global__ __launch_bounds__(128) void zero_small(int* p) {
    p[threadIdx.x] = 0;
}

// Per-bucket edge counts (bucket = dst >> 10).
__global__ __launch_bounds__(256) void hist_buckets(const int* __restrict__ dst, int E,
                                                    int* __restrict__ bucket_count) {
    __shared__ int h[NB_MAX];
    const int t = threadIdx.x;
    if (t < NB_MAX) h[t] = 0;
    __syncthreads();
    const int e0 = blockIdx.x * PART_CHUNK;
    #pragma unroll
    for (int q = 0; q < PART_VE; ++q) {
        const int e = e0 + q * 256 + t;
        if (e < E) atomicAdd(&h[dst[e] >> 10], 1);
    }
    __syncthreads();
    if (t < NB_MAX && h[t]) atomicAdd(&bucket_count[t], h[t]);
}

// Single-wave exclusive scan of the 128 bucket counts (lane owns 2 buckets).
__global__ __launch_bounds__(64) void scan_buckets(const int* __restrict__ bucket_count,
                                                   int* __restrict__ bucket_base,
                                                   int* __restrict__ bucket_cursor,
                                                   int* __restrict__ rowptr, int N, int E) {
    const int t = threadIdx.x;
    const int v0 = bucket_count[2 * t], v1 = bucket_count[2 * t + 1];
    const int tsum = v0 + v1;
    int inc = tsum;
    #pragma unroll
    for (int off = 1; off < 64; off <<= 1) {
        int u = __shfl_up(inc, off, 64);
        if (t >= off) inc += u;
    }
    const int excl = inc - tsum;
    bucket_base[2 * t] = excl;
    bucket_base[2 * t + 1] = excl + v0;
    bucket_cursor[2 * t] = excl;
    bucket_cursor[2 * t + 1] = excl + v0;
    if (t == 63) bucket_base[NB_MAX] = inc;   // == E
    if (t == 0) rowptr[N] = E;
}

// Partition edges into per-bucket contiguous regions with coalesced writes.
// Packed record: (d & 1023) << 17 | src.
__global__ __launch_bounds__(256) void partition_edges(
    const int* __restrict__ ei, int E,
    int* __restrict__ bucket_cursor, int* __restrict__ packed_out)
{
    __shared__ int stage[PART_CHUNK];
    __shared__ unsigned char bstage[PART_CHUNK];
    __shared__ int hist[NB_MAX], lbase[NB_MAX], gbase[NB_MAX], lcur[NB_MAX];
    const int t = threadIdx.x;
    const int e0 = blockIdx.x * PART_CHUNK;
    if (t < NB_MAX) hist[t] = 0;
    __syncthreads();

    int pk[PART_VE], bk[PART_VE];
    #pragma unroll
    for (int q = 0; q < PART_VE; ++q) {
        const int e = e0 + q * 256 + t;
        bk[q] = -1;
        if (e < E) {
            const int s = ei[e];
            const int d = ei[E + e];
            bk[q] = d >> 10;
            pk[q] = ((d & 1023) << 17) | s;
            atomicAdd(&hist[bk[q]], 1);
        }
    }
    __syncthreads();

    if (t < 64) {
        const int v0 = hist[2 * t], v1 = hist[2 * t + 1];
        const int tsum = v0 + v1;
        int inc = tsum;
        #pragma unroll
        for (int off = 1; off < 64; off <<= 1) {
            int u = __shfl_up(inc, off, 64);
            if (t >= off) inc += u;
        }
        const int excl = inc - tsum;
        lbase[2 * t] = excl;        lbase[2 * t + 1] = excl + v0;
        lcur[2 * t]  = excl;        lcur[2 * t + 1]  = excl + v0;
        gbase[2 * t]     = v0 ? atomicAdd(&bucket_cursor[2 * t], v0) : 0;
        gbase[2 * t + 1] = v1 ? atomicAdd(&bucket_cursor[2 * t + 1], v1) : 0;
    }
    __syncthreads();

    #pragma unroll
    for (int q = 0; q < PART_VE; ++q) {
        if (bk[q] >= 0) {
            const int p = atomicAdd(&lcur[bk[q]], 1);
            stage[p]  = pk[q];
            bstage[p] = (unsigned char)bk[q];
        }
    }
    __syncthreads();

    const int total = (E - e0 < PART_CHUNK) ? (E - e0) : PART_CHUNK;
    for (int i = t; i < total; i += 256) {
        const int b = bstage[i];
        packed_out[gbase[b] + (i - lbase[b])] = stage[i];
    }
}

// One block per 1024-node bucket: local histogram -> local scan -> rowptr/norm
// -> LDS-cursor scatter into this bucket's contiguous csr segment.
__global__ __launch_bounds__(1024) void build_csr(
    const int* __restrict__ packed, const int* __restrict__ bucket_base,
    int N, int* __restrict__ rowptr, float* __restrict__ normv,
    int* __restrict__ csr)
{
    __shared__ int ldeg[1024];
    __shared__ int lrow[1024];
    __shared__ int wtot[16];
    const int b = blockIdx.x;
    const int node0 = b << 10;
    const int t = threadIdx.x;
    const int jb = bucket_base[b], je = bucket_base[b + 1];

    ldeg[t] = 0;
    __syncthreads();
    for (int j = jb + t; j < je; j += 1024)
        atomicAdd(&ldeg[packed[j] >> 17], 1);
    __syncthreads();

    const int lane = t & 63, wid = t >> 6;
    const int v = ldeg[t];
    int inc = v;
    #pragma unroll
    for (int off = 1; off < 64; off <<= 1) {
        int u = __shfl_up(inc, off, 64);
        if (lane >= off) inc += u;
    }
    if (lane == 63) wtot[wid] = inc;
    __syncthreads();
    int woff = 0;
    for (int w = 0; w < wid; ++w) woff += wtot[w];
    const int excl = woff + inc - v;
    lrow[t] = excl;
    __syncthreads();

    const int nloc = (N - node0 < 1024) ? (N - node0) : 1024;
    if (t < nloc) {
        rowptr[node0 + t] = jb + excl;
        normv[node0 + t] = rsqrtf((float)(v + 1));   // +1 self-loop
    }
    __syncthreads();

    for (int j = jb + t; j < je; j += 1024) {
        const int pv = packed[j];
        const int slot = jb + atomicAdd(&lrow[pv >> 17], 1);
        csr[slot] = pv & 0x1FFFF;
    }
}

// Transpose-convert weights for MFMA B-operand: W1h[n][k] = (half)W1[k][n],
// W2h[n][k] = (half)W2[k][n]. 16384 + 8192 elems; one tiny kernel.
__global__ __launch_bounds__(256) void prep_weights(
    const float* __restrict__ W1, const float* __restrict__ W2,
    __half* __restrict__ W1h, __half* __restrict__ W2h)
{
    const int idx = blockIdx.x * 256 + threadIdx.x;
    if (idx < 128 * 128) {
        const int n = idx >> 7, k = idx & 127;
        W1h[idx] = __float2half(W1[k * 128 + n]);
    }
    const int idx2 = idx - 128 * 128;
    if (idx2 >= 0 && idx2 < 64 * 128) {
        const int n = idx2 >> 7, k = idx2 & 127;
        W2h[idx2] = __float2half(W2[k * 64 + n]);
    }
}

// Layer-1 MFMA GEMM: H'[row,0..127] = norm[row]*(x[row,:]@W1), fp16 out.
// Split-A (x = hi + lo) so only W-fp16 quantization enters the result.
// 256 thr = 4 waves; wave w owns rows w*16..+15, all 8 col-tiles.
__global__ __launch_bounds__(256) void gemm128_mfma(
    const float* __restrict__ A, const __half* __restrict__ Wh,  // [n][k]
    const float* __restrict__ norm, __half* __restrict__ Hout, int nrows)
{
    __shared__ _Float16 Ah[64 * LDA];
    __shared__ _Float16 Al[64 * LDA];
    __shared__ _Float16 Bh[128 * LDA];
    const int t = threadIdx.x;
    const int row0 = blockIdx.x * 64;

    {   // stage A split hi/lo: thread t -> row t>>2, 32-col segment (t&3)*32
        const int r = t >> 2;
        const int seg = (t & 3) * 32;
        int grow = row0 + r;
        if (grow > nrows - 1) grow = nrows - 1;
        const float* src = &A[(size_t)grow * K_DIM + seg];
        _Float16 hi[32], lo[32];
        #pragma unroll
        for (int i = 0; i < 8; ++i) {
            float4 v = *(const float4*)&src[i * 4];
            const float vf[4] = {v.x, v.y, v.z, v.w};
            #pragma unroll
            for (int j = 0; j < 4; ++j) {
                _Float16 h = (_Float16)vf[j];
                hi[i * 4 + j] = h;
                lo[i * 4 + j] = (_Float16)(vf[j] - (float)h);
            }
        }
        #pragma unroll
        for (int c = 0; c < 4; ++c) {
            *(half8*)&Ah[r * LDA + seg + c * 8] = *(half8*)&hi[c * 8];
            *(half8*)&Al[r * LDA + seg + c * 8] = *(half8*)&lo[c * 8];
        }
    }
    {   // stage B: 128x128 halfs = 2048 b128-chunks, 8 per thread
        const _Float16* wf = (const _Float16*)Wh;
        #pragma unroll
        for (int i = 0; i < 8; ++i) {
            const int id = i * 256 + t;
            const int n = id >> 4, kc = id & 15;
            *(half8*)&Bh[n * LDA + kc * 8] = *(const half8*)&wf[n * 128 + kc * 8];
        }
    }
    __syncthreads();

    const int lane = t & 63, wave = t >> 6;
    const int m = lane & 15, quad = lane >> 4;
    const int arow = wave * 16 + m;

    floatx4 acc[8];
    #pragma unroll
    for (int nt = 0; nt < 8; ++nt) acc[nt] = (floatx4){0.f, 0.f, 0.f, 0.f};

    #pragma unroll
    for (int k0 = 0; k0 < 128; k0 += 32) {
        half8 ah = *(const half8*)&Ah[arow * LDA + k0 + quad * 8];
        half8 al = *(const half8*)&Al[arow * LDA + k0 + quad * 8];
        #pragma unroll
        for (int nt = 0; nt < 8; ++nt) {
            half8 b = *(const half8*)&Bh[(nt * 16 + m) * LDA + k0 + quad * 8];
            acc[nt] = __builtin_amdgcn_mfma_f32_16x16x32_f16(ah, b, acc[nt], 0, 0, 0);
            acc[nt] = __builtin_amdgcn_mfma_f32_16x16x32_f16(al, b, acc[nt], 0, 0, 0);
        }
    }

    // D: row = quad*4 + reg, col = nt*16 + m
    #pragma unroll
    for (int reg = 0; reg < 4; ++reg) {
        const int row = row0 + wave * 16 + quad * 4 + reg;
        if (row < nrows) {
            const float nr = norm[row];
            #pragma unroll
            for (int nt = 0; nt < 8; ++nt)
                Hout[(size_t)row * 128 + nt * 16 + m] = __float2half(acc[nt][reg] * nr);
        }
    }
}

// Fused layer-1 aggregation + layer-2 GEMM.
// Block owns 64 dst rows: 4 waves x 16 sequential dsts. Per dst, the R11
// gather loop (full 256 B rows, 8-deep pipeline, one wave per dst) computes
// relu(nd * (sum h1'[s] + h1'[d]) + b1) -> LDS tile [64][128]. Then the
// proven gemm64 MFMA body multiplies the tile by LDS-staged W2 and writes
// h2'[row,0..63] = norm[row]*(tile@W2) fp16. agg1 never touches HBM.
__global__ __launch_bounds__(256) void gather_relu_gemm64(
    const int* __restrict__ rowptr, const int* __restrict__ csr,
    const float* __restrict__ norm, const __half* __restrict__ h,
    const float* __restrict__ bias, const __half* __restrict__ W2h,
    __half* __restrict__ h2, int n)
{
    __shared__ _Float16 Ah[64 * LDA];
    __shared__ _Float16 Bh[64 * LDA];
    const int t = threadIdx.x;
    const int lane = t & 63, wave = t >> 6;
    const int row0 = blockIdx.x * 64;
    const __half2* hp = (const __half2*)h;   // row stride 64 half2 (256 B)

    {   // stage W2 [64][128] halfs = 1024 b128-chunks, 4 per thread
        const _Float16* wf = (const _Float16*)W2h;
        #pragma unroll
        for (int i = 0; i < 4; ++i) {
            const int id = i * 256 + t;
            const int nn = id >> 4, kc = id & 15;
            *(half8*)&Bh[nn * LDA + kc * 8] = *(const half8*)&wf[nn * 128 + kc * 8];
        }
    }

    const float bx = bias[2 * lane], by = bias[2 * lane + 1];

    for (int i = 0; i < 16; ++i) {
        const int dl = (wave << 4) + i;
        const int d = __builtin_amdgcn_readfirstlane(row0 + dl);
        float ox = 0.f, oy = 0.f;
        if (d < n) {
            const int jb = rowptr[d], je = rowptr[d + 1];
            float ax[8] = {}, ay[8] = {};
            int j = jb;
            if (j + 8 <= je) {
                int s[8];
                #pragma unroll
                for (int q = 0; q < 8; ++q) s[q] = csr[j + q];
                for (; j + 16 <= je; j += 8) {
                    int sn[8];
                    #pragma unroll
                    for (int q = 0; q < 8; ++q) sn[q] = csr[j + 8 + q];
                    #pragma unroll
                    for (int q = 0; q < 8; ++q) {
                        const float2 v = __half22float2(hp[(size_t)s[q] * 64 + lane]);
                        ax[q] += v.x; ay[q] += v.y;
                    }
                    #pragma unroll
                    for (int q = 0; q < 8; ++q) s[q] = sn[q];
                }
                #pragma unroll
                for (int q = 0; q < 8; ++q) {
                    const float2 v = __half22float2(hp[(size_t)s[q] * 64 + lane]);
                    ax[q] += v.x; ay[q] += v.y;
                }
                j += 8;
            }
            for (; j < je; ++j) {
                const float2 v = __half22float2(hp[(size_t)csr[j] * 64 + lane]);
                ax[0] += v.x; ay[0] += v.y;
            }

            const float2 sv = __half22float2(hp[(size_t)d * 64 + lane]);  // self (premult)
            const float nd = norm[d];
            float sx = ((ax[0] + ax[1]) + (ax[2] + ax[3])) + ((ax[4] + ax[5]) + (ax[6] + ax[7])) + sv.x;
            float sy = ((ay[0] + ay[1]) + (ay[2] + ay[3])) + ((ay[4] + ay[5]) + (ay[6] + ay[7])) + sv.y;
            ox = fmaxf(fmaf(nd, sx, bx), 0.f);
            oy = fmaxf(fmaf(nd, sy, by), 0.f);
        }
        ((__half2*)Ah)[dl * (LDA / 2) + lane] = __floats2half2_rn(ox, oy);
    }
    __syncthreads();

    // gemm64 MFMA body: h2[row,0..63] = norm[row] * (Ah @ W2)
    const int m = lane & 15, quad = lane >> 4;
    const int arow = wave * 16 + m;

    floatx4 acc[4];
    #pragma unroll
    for (int nt = 0; nt < 4; ++nt) acc[nt] = (floatx4){0.f, 0.f, 0.f, 0.f};

    #pragma unroll
    for (int k0 = 0; k0 < 128; k0 += 32) {
        half8 ah = *(const half8*)&Ah[arow * LDA + k0 + quad * 8];
        #pragma unroll
        for (int nt = 0; nt < 4; ++nt) {
            half8 b = *(const half8*)&Bh[(nt * 16 + m) * LDA + k0 + quad * 8];
            acc[nt] = __builtin_amdgcn_mfma_f32_16x16x32_f16(ah, b, acc[nt], 0, 0, 0);
        }
    }

    #pragma unroll
    for (int reg = 0; reg < 4; ++reg) {
        const int row = row0 + wave * 16 + quad * 4 + reg;
        if (row < n) {
            const float nr = norm[row];
            #pragma unroll
            for (int nt = 0; nt < 4; ++nt)
                h2[(size_t)row * 64 + nt * 16 + m] = __float2half(acc[nt][reg] * nr);
        }
    }
}

// Layer-2 aggregation + row softmax (scalar-path); h' fp16, 64 cols = 64 lanes.
__global__ __launch_bounds__(256) void gather_softmax(
    const int* __restrict__ rowptr, const int* __restrict__ csr,
    const float* __restrict__ norm, const __half* __restrict__ h,
    const float* __restrict__ bias, float* __restrict__ out, int n)
{
    const int lane = threadIdx.x & 63;
    const int d = __builtin_amdgcn_readfirstlane(blockIdx.x * 4 + (threadIdx.x >> 6));
    if (d >= n) return;

    const int jb = rowptr[d], je = rowptr[d + 1];
    float acc[8] = {};
    int j = jb;
    if (j + 8 <= je) {
        int s[8];
        #pragma unroll
        for (int q = 0; q < 8; ++q) s[q] = csr[j + q];
        for (; j + 16 <= je; j += 8) {
            int sn[8];
            #pragma unroll
            for (int q = 0; q < 8; ++q) sn[q] = csr[j + 8 + q];
            #pragma unroll
            for (int q = 0; q < 8; ++q)
                acc[q] += __half2float(h[(size_t)s[q] * 64 + lane]);
            #pragma unroll
            for (int q = 0; q < 8; ++q) s[q] = sn[q];
        }
        #pragma unroll
        for (int q = 0; q < 8; ++q)
            acc[q] += __half2float(h[(size_t)s[q] * 64 + lane]);
        j += 8;
    }
    for (; j < je; ++j)
        acc[0] += __half2float(h[(size_t)csr[j] * 64 + lane]);

    const float nd = norm[d];
    float tot = ((acc[0] + acc[1]) + (acc[2] + acc[3])) +
                ((acc[4] + acc[5]) + (acc[6] + acc[7])) +
                __half2float(h[(size_t)d * 64 + lane]);
    float a = fmaf(nd, tot, bias[lane]);
    float m = a;
    #pragma unroll
    for (int off = 32; off; off >>= 1) m = fmaxf(m, __shfl_xor(m, off, 64));
    float ex = expf(a - m);
    float ssum = ex;
    #pragma unroll
    for (int off = 32; off; off >>= 1) ssum += __shfl_xor(ssum, off, 64);
    out[(size_t)d * 64 + lane] = ex / ssum;
}

extern "C" void kernel_launch(void* const* d_in, const int* in_sizes, int n_in,
                              void* d_out, int out_size, void* d_ws, size_t ws_size,
                              hipStream_t stream) {
    const float* x  = (const float*)d_in[0];
    const int*   ei = (const int*)d_in[1];
    const float* W1 = (const float*)d_in[2];
    const float* b1 = (const float*)d_in[3];
    const float* W2 = (const float*)d_in[4];
    const float* b2 = (const float*)d_in[5];
    float* out = (float*)d_out;

    const int N = in_sizes[0] / K_DIM;     // 100000 (<= 2^17 required)
    const int E = in_sizes[1] / 2;         // 1600000
    const int NBUCK = (N + 1023) >> 10;    // 98 buckets of 1024 nodes

    // Workspace layout (peak ~65 MB)
    size_t o = 0;
    char* base = (char*)d_ws;
    auto alloc = [&](size_t elems) {       // elems in 4-byte units
        void* p = base + o;
        o += (elems * 4 + 1023) & ~(size_t)1023;
        return p;
    };
    int*    bcount = (int*)   alloc(NB_MAX);
    int*    bbase  = (int*)   alloc(NB_MAX + 1);
    int*    bcur   = (int*)   alloc(NB_MAX);
    int*    rowptr = (int*)   alloc(N + 1);
    float*  norm   = (float*) alloc(N);
    int*    packed = (int*)   alloc(E);
    int*    csr    = (int*)   alloc(E);
    __half* W1h    = (__half*)alloc(128 * 128 / 2);
    __half* W2h    = (__half*)alloc(64 * 128 / 2);
    __half* h1h    = (__half*)alloc((size_t)N * 64);  // fp16 [Nx128]
    __half* h2h    = (__half*)alloc((size_t)N * 32);  // fp16 [Nx64] (separate: read h1h while writing h2h)

    const int nb_c = (E + PART_CHUNK - 1) / PART_CHUNK;   // partition chunks
    const int nb_g = (N + 3) / 4;
    const int nb_m = (N + 63) / 64;

    // ---- CSR build (two-level partition) + weight prep ----
    zero_small<<<1, NB_MAX, 0, stream>>>(bcount);
    prep_weights<<<96, 256, 0, stream>>>(W1, W2, W1h, W2h);
    hist_buckets<<<nb_c, 256, 0, stream>>>(ei + E, E, bcount);
    scan_buckets<<<1, 64, 0, stream>>>(bcount, bbase, bcur, rowptr, N, E);
    partition_edges<<<nb_c, 256, 0, stream>>>(ei, E, bcur, packed);
    build_csr<<<NBUCK, 1024, 0, stream>>>(packed, bbase, N, rowptr, norm, csr);

    // ---- Layer 1: h1' = norm .* (x@W1), fp16 [N x 128], MFMA split-A ----
    gemm128_mfma<<<nb_m, 256, 0, stream>>>(x, W1h, norm, h1h, N);

    // ---- Fused: agg1 = relu(gather(h1')) in LDS; h2' = norm .* (agg1@W2) ----
    gather_relu_gemm64<<<nb_m, 256, 0, stream>>>(rowptr, csr, norm, h1h, b1, W2h, h2h, N);

    // ---- Layer 2 aggregation + softmax ----
    gather_softmax<<<nb_g, 256, 0, stream>>>(rowptr, csr, norm, h2h, b2, out, N);
}

// Round 3
// 297.801 us; speedup vs baseline: 1.1367x; 1.0989x over previous
//
#include <hip/hip_runtime.h>
#include <hip/hip_bf16.h>
#include <hip/hip_fp16.h>

// GCN: out = softmax( GCNConv2( relu( GCNConv1(x) ) ) )
// GCNConv(x) = D^-1/2 (A+I) D^-1/2 (x W) + b
//
// Round 14:
//  (a) Fused gather+gemm64 kept, but block widened to 512 threads (8 waves,
//      8 dsts/wave instead of 4 waves x 16). R13's 100 us was an occupancy
//      loss: 34.8 KB LDS -> 4 blocks/CU x 4 waves = 16 waves/CU ceiling vs
//      the unfused gather's ~21; BW fell 3.6 -> 2.07 TB/s proportionally.
//      512-thread blocks at the same LDS give 32 waves/CU ceiling. MFMA
//      epilogue splits 8 ways: wave w -> rows (w&3)*16..+15, col-pair w>>2.
//  (b) Rest unchanged (R11 gather inner loop, MFMA GEMMs, two-level CSR).
// Requires N <= 2^17. N = 100000 here.

#define K_DIM 128
#define PART_VE 16
#define PART_CHUNK 4096   // 256 threads * 16 edges
#define NB_MAX 128        // bucket array size (N <= 128*1024)
#define LDA 136           // LDS row stride in halfs (128 + 8 pad)

typedef _Float16 half8 __attribute__((ext_vector_type(8)));
typedef float floatx4 __attribute__((ext_vector_type(4)));

__global__ __launch_bounds__(128) void zero_small(int* p) {
    p[threadIdx.x] = 0;
}

// Per-bucket edge counts (bucket = dst >> 10).
__global__ __launch_bounds__(256) void hist_buckets(const int* __restrict__ dst, int E,
                                                    int* __restrict__ bucket_count) {
    __shared__ int h[NB_MAX];
    const int t = threadIdx.x;
    if (t < NB_MAX) h[t] = 0;
    __syncthreads();
    const int e0 = blockIdx.x * PART_CHUNK;
    #pragma unroll
    for (int q = 0; q < PART_VE; ++q) {
        const int e = e0 + q * 256 + t;
        if (e < E) atomicAdd(&h[dst[e] >> 10], 1);
    }
    __syncthreads();
    if (t < NB_MAX && h[t]) atomicAdd(&bucket_count[t], h[t]);
}

// Single-wave exclusive scan of the 128 bucket counts (lane owns 2 buckets).
__global__ __launch_bounds__(64) void scan_buckets(const int* __restrict__ bucket_count,
                                                   int* __restrict__ bucket_base,
                                                   int* __restrict__ bucket_cursor,
                                                   int* __restrict__ rowptr, int N, int E) {
    const int t = threadIdx.x;
    const int v0 = bucket_count[2 * t], v1 = bucket_count[2 * t + 1];
    const int tsum = v0 + v1;
    int inc = tsum;
    #pragma unroll
    for (int off = 1; off < 64; off <<= 1) {
        int u = __shfl_up(inc, off, 64);
        if (t >= off) inc += u;
    }
    const int excl = inc - tsum;
    bucket_base[2 * t] = excl;
    bucket_base[2 * t + 1] = excl + v0;
    bucket_cursor[2 * t] = excl;
    bucket_cursor[2 * t + 1] = excl + v0;
    if (t == 63) bucket_base[NB_MAX] = inc;   // == E
    if (t == 0) rowptr[N] = E;
}

// Partition edges into per-bucket contiguous regions with coalesced writes.
// Packed record: (d & 1023) << 17 | src.
__global__ __launch_bounds__(256) void partition_edges(
    const int* __restrict__ ei, int E,
    int* __restrict__ bucket_cursor, int* __restrict__ packed_out)
{
    __shared__ int stage[PART_CHUNK];
    __shared__ unsigned char bstage[PART_CHUNK];
    __shared__ int hist[NB_MAX], lbase[NB_MAX], gbase[NB_MAX], lcur[NB_MAX];
    const int t = threadIdx.x;
    const int e0 = blockIdx.x * PART_CHUNK;
    if (t < NB_MAX) hist[t] = 0;
    __syncthreads();

    int pk[PART_VE], bk[PART_VE];
    #pragma unroll
    for (int q = 0; q < PART_VE; ++q) {
        const int e = e0 + q * 256 + t;
        bk[q] = -1;
        if (e < E) {
            const int s = ei[e];
            const int d = ei[E + e];
            bk[q] = d >> 10;
            pk[q] = ((d & 1023) << 17) | s;
            atomicAdd(&hist[bk[q]], 1);
        }
    }
    __syncthreads();

    if (t < 64) {
        const int v0 = hist[2 * t], v1 = hist[2 * t + 1];
        const int tsum = v0 + v1;
        int inc = tsum;
        #pragma unroll
        for (int off = 1; off < 64; off <<= 1) {
            int u = __shfl_up(inc, off, 64);
            if (t >= off) inc += u;
        }
        const int excl = inc - tsum;
        lbase[2 * t] = excl;        lbase[2 * t + 1] = excl + v0;
        lcur[2 * t]  = excl;        lcur[2 * t + 1]  = excl + v0;
        gbase[2 * t]     = v0 ? atomicAdd(&bucket_cursor[2 * t], v0) : 0;
        gbase[2 * t + 1] = v1 ? atomicAdd(&bucket_cursor[2 * t + 1], v1) : 0;
    }
    __syncthreads();

    #pragma unroll
    for (int q = 0; q < PART_VE; ++q) {
        if (bk[q] >= 0) {
            const int p = atomicAdd(&lcur[bk[q]], 1);
            stage[p]  = pk[q];
            bstage[p] = (unsigned char)bk[q];
        }
    }
    __syncthreads();

    const int total = (E - e0 < PART_CHUNK) ? (E - e0) : PART_CHUNK;
    for (int i = t; i < total; i += 256) {
        const int b = bstage[i];
        packed_out[gbase[b] + (i - lbase[b])] = stage[i];
    }
}

// One block per 1024-node bucket: local histogram -> local scan -> rowptr/norm
// -> LDS-cursor scatter into this bucket's contiguous csr segment.
__global__ __launch_bounds__(1024) void build_csr(
    const int* __restrict__ packed, const int* __restrict__ bucket_base,
    int N, int* __restrict__ rowptr, float* __restrict__ normv,
    int* __restrict__ csr)
{
    __shared__ int ldeg[1024];
    __shared__ int lrow[1024];
    __shared__ int wtot[16];
    const int b = blockIdx.x;
    const int node0 = b << 10;
    const int t = threadIdx.x;
    const int jb = bucket_base[b], je = bucket_base[b + 1];

    ldeg[t] = 0;
    __syncthreads();
    for (int j = jb + t; j < je; j += 1024)
        atomicAdd(&ldeg[packed[j] >> 17], 1);
    __syncthreads();

    const int lane = t & 63, wid = t >> 6;
    const int v = ldeg[t];
    int inc = v;
    #pragma unroll
    for (int off = 1; off < 64; off <<= 1) {
        int u = __shfl_up(inc, off, 64);
        if (lane >= off) inc += u;
    }
    if (lane == 63) wtot[wid] = inc;
    __syncthreads();
    int woff = 0;
    for (int w = 0; w < wid; ++w) woff += wtot[w];
    const int excl = woff + inc - v;
    lrow[t] = excl;
    __syncthreads();

    const int nloc = (N - node0 < 1024) ? (N - node0) : 1024;
    if (t < nloc) {
        rowptr[node0 + t] = jb + excl;
        normv[node0 + t] = rsqrtf((float)(v + 1));   // +1 self-loop
    }
    __syncthreads();

    for (int j = jb + t; j < je; j += 1024) {
        const int pv = packed[j];
        const int slot = jb + atomicAdd(&lrow[pv >> 17], 1);
        csr[slot] = pv & 0x1FFFF;
    }
}

// Transpose-convert weights for MFMA B-operand: W1h[n][k] = (half)W1[k][n],
// W2h[n][k] = (half)W2[k][n]. 16384 + 8192 elems; one tiny kernel.
__global__ __launch_bounds__(256) void prep_weights(
    const float* __restrict__ W1, const float* __restrict__ W2,
    __half* __restrict__ W1h, __half* __restrict__ W2h)
{
    const int idx = blockIdx.x * 256 + threadIdx.x;
    if (idx < 128 * 128) {
        const int n = idx >> 7, k = idx & 127;
        W1h[idx] = __float2half(W1[k * 128 + n]);
    }
    const int idx2 = idx - 128 * 128;
    if (idx2 >= 0 && idx2 < 64 * 128) {
        const int n = idx2 >> 7, k = idx2 & 127;
        W2h[idx2] = __float2half(W2[k * 64 + n]);
    }
}

// Layer-1 MFMA GEMM: H'[row,0..127] = norm[row]*(x[row,:]@W1), fp16 out.
// Split-A (x = hi + lo) so only W-fp16 quantization enters the result.
// 256 thr = 4 waves; wave w owns rows w*16..+15, all 8 col-tiles.
__global__ __launch_bounds__(256) void gemm128_mfma(
    const float* __restrict__ A, const __half* __restrict__ Wh,  // [n][k]
    const float* __restrict__ norm, __half* __restrict__ Hout, int nrows)
{
    __shared__ _Float16 Ah[64 * LDA];
    __shared__ _Float16 Al[64 * LDA];
    __shared__ _Float16 Bh[128 * LDA];
    const int t = threadIdx.x;
    const int row0 = blockIdx.x * 64;

    {   // stage A split hi/lo: thread t -> row t>>2, 32-col segment (t&3)*32
        const int r = t >> 2;
        const int seg = (t & 3) * 32;
        int grow = row0 + r;
        if (grow > nrows - 1) grow = nrows - 1;
        const float* src = &A[(size_t)grow * K_DIM + seg];
        _Float16 hi[32], lo[32];
        #pragma unroll
        for (int i = 0; i < 8; ++i) {
            float4 v = *(const float4*)&src[i * 4];
            const float vf[4] = {v.x, v.y, v.z, v.w};
            #pragma unroll
            for (int j = 0; j < 4; ++j) {
                _Float16 h = (_Float16)vf[j];
                hi[i * 4 + j] = h;
                lo[i * 4 + j] = (_Float16)(vf[j] - (float)h);
            }
        }
        #pragma unroll
        for (int c = 0; c < 4; ++c) {
            *(half8*)&Ah[r * LDA + seg + c * 8] = *(half8*)&hi[c * 8];
            *(half8*)&Al[r * LDA + seg + c * 8] = *(half8*)&lo[c * 8];
        }
    }
    {   // stage B: 128x128 halfs = 2048 b128-chunks, 8 per thread
        const _Float16* wf = (const _Float16*)Wh;
        #pragma unroll
        for (int i = 0; i < 8; ++i) {
            const int id = i * 256 + t;
            const int n = id >> 4, kc = id & 15;
            *(half8*)&Bh[n * LDA + kc * 8] = *(const half8*)&wf[n * 128 + kc * 8];
        }
    }
    __syncthreads();

    const int lane = t & 63, wave = t >> 6;
    const int m = lane & 15, quad = lane >> 4;
    const int arow = wave * 16 + m;

    floatx4 acc[8];
    #pragma unroll
    for (int nt = 0; nt < 8; ++nt) acc[nt] = (floatx4){0.f, 0.f, 0.f, 0.f};

    #pragma unroll
    for (int k0 = 0; k0 < 128; k0 += 32) {
        half8 ah = *(const half8*)&Ah[arow * LDA + k0 + quad * 8];
        half8 al = *(const half8*)&Al[arow * LDA + k0 + quad * 8];
        #pragma unroll
        for (int nt = 0; nt < 8; ++nt) {
            half8 b = *(const half8*)&Bh[(nt * 16 + m) * LDA + k0 + quad * 8];
            acc[nt] = __builtin_amdgcn_mfma_f32_16x16x32_f16(ah, b, acc[nt], 0, 0, 0);
            acc[nt] = __builtin_amdgcn_mfma_f32_16x16x32_f16(al, b, acc[nt], 0, 0, 0);
        }
    }

    // D: row = quad*4 + reg, col = nt*16 + m
    #pragma unroll
    for (int reg = 0; reg < 4; ++reg) {
        const int row = row0 + wave * 16 + quad * 4 + reg;
        if (row < nrows) {
            const float nr = norm[row];
            #pragma unroll
            for (int nt = 0; nt < 8; ++nt)
                Hout[(size_t)row * 128 + nt * 16 + m] = __float2half(acc[nt][reg] * nr);
        }
    }
}

// Fused layer-1 aggregation + layer-2 GEMM, 512 threads = 8 waves.
// Each wave gathers 8 dst rows (R11 inner loop, full 256 B rows, 8-deep
// pipeline) -> relu'd tile row in LDS. Then 8-way split MFMA: wave w
// computes rows (w&3)*16..+15 x col-pair (w>>2): h2' = norm .* (tile@W2).
// 34.8 KB LDS -> 4 blocks/CU -> 32 waves/CU ceiling (R13's 256-thr version
// capped at 16 waves/CU and lost the gather's memory-level parallelism).
__global__ __launch_bounds__(512, 8) void gather_relu_gemm64(
    const int* __restrict__ rowptr, const int* __restrict__ csr,
    const float* __restrict__ norm, const __half* __restrict__ h,
    const float* __restrict__ bias, const __half* __restrict__ W2h,
    __half* __restrict__ h2, int n)
{
    __shared__ _Float16 Ah[64 * LDA];
    __shared__ _Float16 Bh[64 * LDA];
    const int t = threadIdx.x;
    const int lane = t & 63, wave = t >> 6;
    const int row0 = blockIdx.x * 64;
    const __half2* hp = (const __half2*)h;   // row stride 64 half2 (256 B)

    {   // stage W2 [64][128] halfs = 1024 b128-chunks, 2 per thread
        const _Float16* wf = (const _Float16*)W2h;
        #pragma unroll
        for (int i = 0; i < 2; ++i) {
            const int id = i * 512 + t;
            const int nn = id >> 4, kc = id & 15;
            *(half8*)&Bh[nn * LDA + kc * 8] = *(const half8*)&wf[nn * 128 + kc * 8];
        }
    }

    const float bx = bias[2 * lane], by = bias[2 * lane + 1];

    for (int i = 0; i < 8; ++i) {
        const int dl = (wave << 3) + i;
        const int d = __builtin_amdgcn_readfirstlane(row0 + dl);
        float ox = 0.f, oy = 0.f;
        if (d < n) {
            const int jb = rowptr[d], je = rowptr[d + 1];
            float ax[8] = {}, ay[8] = {};
            int j = jb;
            if (j + 8 <= je) {
                int s[8];
                #pragma unroll
                for (int q = 0; q < 8; ++q) s[q] = csr[j + q];
                for (; j + 16 <= je; j += 8) {
                    int sn[8];
                    #pragma unroll
                    for (int q = 0; q < 8; ++q) sn[q] = csr[j + 8 + q];
                    #pragma unroll
                    for (int q = 0; q < 8; ++q) {
                        const float2 v = __half22float2(hp[(size_t)s[q] * 64 + lane]);
                        ax[q] += v.x; ay[q] += v.y;
                    }
                    #pragma unroll
                    for (int q = 0; q < 8; ++q) s[q] = sn[q];
                }
                #pragma unroll
                for (int q = 0; q < 8; ++q) {
                    const float2 v = __half22float2(hp[(size_t)s[q] * 64 + lane]);
                    ax[q] += v.x; ay[q] += v.y;
                }
                j += 8;
            }
            for (; j < je; ++j) {
                const float2 v = __half22float2(hp[(size_t)csr[j] * 64 + lane]);
                ax[0] += v.x; ay[0] += v.y;
            }

            const float2 sv = __half22float2(hp[(size_t)d * 64 + lane]);  // self (premult)
            const float nd = norm[d];
            float sx = ((ax[0] + ax[1]) + (ax[2] + ax[3])) + ((ax[4] + ax[5]) + (ax[6] + ax[7])) + sv.x;
            float sy = ((ay[0] + ay[1]) + (ay[2] + ay[3])) + ((ay[4] + ay[5]) + (ay[6] + ay[7])) + sv.y;
            ox = fmaxf(fmaf(nd, sx, bx), 0.f);
            oy = fmaxf(fmaf(nd, sy, by), 0.f);
        }
        ((__half2*)Ah)[dl * (LDA / 2) + lane] = __floats2half2_rn(ox, oy);
    }
    __syncthreads();

    // 8-way split gemm64: wave w -> rows (w&3)*16..+15, cols (w>>2)*32..+31
    const int m = lane & 15, quad = lane >> 4;
    const int rw = wave & 3, cw = wave >> 2;
    const int arow = rw * 16 + m;
    const int nt0 = cw * 2;

    floatx4 acc[2];
    #pragma unroll
    for (int nt = 0; nt < 2; ++nt) acc[nt] = (floatx4){0.f, 0.f, 0.f, 0.f};

    #pragma unroll
    for (int k0 = 0; k0 < 128; k0 += 32) {
        half8 ah = *(const half8*)&Ah[arow * LDA + k0 + quad * 8];
        #pragma unroll
        for (int nt = 0; nt < 2; ++nt) {
            half8 b = *(const half8*)&Bh[((nt0 + nt) * 16 + m) * LDA + k0 + quad * 8];
            acc[nt] = __builtin_amdgcn_mfma_f32_16x16x32_f16(ah, b, acc[nt], 0, 0, 0);
        }
    }

    #pragma unroll
    for (int reg = 0; reg < 4; ++reg) {
        const int row = row0 + rw * 16 + quad * 4 + reg;
        if (row < n) {
            const float nr = norm[row];
            #pragma unroll
            for (int nt = 0; nt < 2; ++nt)
                h2[(size_t)row * 64 + (nt0 + nt) * 16 + m] = __float2half(acc[nt][reg] * nr);
        }
    }
}

// Layer-2 aggregation + row softmax (scalar-path); h' fp16, 64 cols = 64 lanes.
__global__ __launch_bounds__(256) void gather_softmax(
    const int* __restrict__ rowptr, const int* __restrict__ csr,
    const float* __restrict__ norm, const __half* __restrict__ h,
    const float* __restrict__ bias, float* __restrict__ out, int n)
{
    const int lane = threadIdx.x & 63;
    const int d = __builtin_amdgcn_readfirstlane(blockIdx.x * 4 + (threadIdx.x >> 6));
    if (d >= n) return;

    const int jb = rowptr[d], je = rowptr[d + 1];
    float acc[8] = {};
    int j = jb;
    if (j + 8 <= je) {
        int s[8];
        #pragma unroll
        for (int q = 0; q < 8; ++q) s[q] = csr[j + q];
        for (; j + 16 <= je; j += 8) {
            int sn[8];
            #pragma unroll
            for (int q = 0; q < 8; ++q) sn[q] = csr[j + 8 + q];
            #pragma unroll
            for (int q = 0; q < 8; ++q)
                acc[q] += __half2float(h[(size_t)s[q] * 64 + lane]);
            #pragma unroll
            for (int q = 0; q < 8; ++q) s[q] = sn[q];
        }
        #pragma unroll
        for (int q = 0; q < 8; ++q)
            acc[q] += __half2float(h[(size_t)s[q] * 64 + lane]);
        j += 8;
    }
    for (; j < je; ++j)
        acc[0] += __half2float(h[(size_t)csr[j] * 64 + lane]);

    const float nd = norm[d];
    float tot = ((acc[0] + acc[1]) + (acc[2] + acc[3])) +
                ((acc[4] + acc[5]) + (acc[6] + acc[7])) +
                __half2float(h[(size_t)d * 64 + lane]);
    float a = fmaf(nd, tot, bias[lane]);
    float m = a;
    #pragma unroll
    for (int off = 32; off; off >>= 1) m = fmaxf(m, __shfl_xor(m, off, 64));
    float ex = expf(a - m);
    float ssum = ex;
    #pragma unroll
    for (int off = 32; off; off >>= 1) ssum += __shfl_xor(ssum, off, 64);
    out[(size_t)d * 64 + lane] = ex / ssum;
}

extern "C" void kernel_launch(void* const* d_in, const int* in_sizes, int n_in,
                              void* d_out, int out_size, void* d_ws, size_t ws_size,
                              hipStream_t stream) {
    const float* x  = (const float*)d_in[0];
    const int*   ei = (const int*)d_in[1];
    const float* W1 = (const float*)d_in[2];
    const float* b1 = (const float*)d_in[3];
    const float* W2 = (const float*)d_in[4];
    const float* b2 = (const float*)d_in[5];
    float* out = (float*)d_out;

    const int N = in_sizes[0] / K_DIM;     // 100000 (<= 2^17 required)
    const int E = in_sizes[1] / 2;         // 1600000
    const int NBUCK = (N + 1023) >> 10;    // 98 buckets of 1024 nodes

    // Workspace layout (peak ~65 MB)
    size_t o = 0;
    char* base = (char*)d_ws;
    auto alloc = [&](size_t elems) {       // elems in 4-byte units
        void* p = base + o;
        o += (elems * 4 + 1023) & ~(size_t)1023;
        return p;
    };
    int*    bcount = (int*)   alloc(NB_MAX);
    int*    bbase  = (int*)   alloc(NB_MAX + 1);
    int*    bcur   = (int*)   alloc(NB_MAX);
    int*    rowptr = (int*)   alloc(N + 1);
    float*  norm   = (float*) alloc(N);
    int*    packed = (int*)   alloc(E);
    int*    csr    = (int*)   alloc(E);
    __half* W1h    = (__half*)alloc(128 * 128 / 2);
    __half* W2h    = (__half*)alloc(64 * 128 / 2);
    __half* h1h    = (__half*)alloc((size_t)N * 64);  // fp16 [Nx128]
    __half* h2h    = (__half*)alloc((size_t)N * 32);  // fp16 [Nx64]

    const int nb_c = (E + PART_CHUNK - 1) / PART_CHUNK;   // partition chunks
    const int nb_g = (N + 3) / 4;
    const int nb_m = (N + 63) / 64;

    // ---- CSR build (two-level partition) + weight prep ----
    zero_small<<<1, NB_MAX, 0, stream>>>(bcount);
    prep_weights<<<96, 256, 0, stream>>>(W1, W2, W1h, W2h);
    hist_buckets<<<nb_c, 256, 0, stream>>>(ei + E, E, bcount);
    scan_buckets<<<1, 64, 0, stream>>>(bcount, bbase, bcur, rowptr, N, E);
    partition_edges<<<nb_c, 256, 0, stream>>>(ei, E, bcur, packed);
    build_csr<<<NBUCK, 1024, 0, stream>>>(packed, bbase, N, rowptr, norm, csr);

    // ---- Layer 1: h1' = norm .* (x@W1), fp16 [N x 128], MFMA split-A ----
    gemm128_mfma<<<nb_m, 256, 0, stream>>>(x, W1h, norm, h1h, N);

    // ---- Fused: agg1 = relu(gather(h1')) in LDS; h2' = norm .* (agg1@W2) ----
    gather_relu_gemm64<<<nb_m, 512, 0, stream>>>(rowptr, csr, norm, h1h, b1, W2h, h2h, N);

    // ---- Layer 2 aggregation + softmax ----
    gather_softmax<<<nb_g, 256, 0, stream>>>(rowptr, csr, norm, h2h, b2, out, N);
}

// Round 4
// 296.180 us; speedup vs baseline: 1.1429x; 1.0055x over previous
//
#include <hip/hip_runtime.h>
#include <hip/hip_bf16.h>
#include <hip/hip_fp16.h>

// GCN: out = softmax( GCNConv2( relu( GCNConv1(x) ) ) )
// GCNConv(x) = D^-1/2 (A+I) D^-1/2 (x W) + b
//
// Round 15:
//  (a) Fused gather+gemm64 made BARRIER-FREE: each of 8 waves owns 8 dst
//      rows, gathers into its own LDS strip, then runs a wave-local
//      16x16x32 MFMA (A rows 8..15 are the neighbor strip's bytes = garbage,
//      but D row r depends only on A row r, so garbage stays in D rows 8..15
//      which are never stored). The per-tile __syncthreads of R14 (straggler
//      tax: max-of-8-waves Poisson gather time, ~12%) and the serialized
//      epilogue are gone; waves free-run, MFMA overlaps other waves' loads.
//      LDS 37 KB (8 pad rows for wave 7's A-read overrun) -> still 4 blk/CU.
//  (b) zero_small kernel replaced by hipMemsetAsync (one fewer dispatch).
//  (c) Rest unchanged (R11 gather inner loop, MFMA GEMMs, two-level CSR).
// Requires N <= 2^17. N = 100000 here.

#define K_DIM 128
#define PART_VE 16
#define PART_CHUNK 4096   // 256 threads * 16 edges
#define NB_MAX 128        // bucket array size (N <= 128*1024)
#define LDA 136           // LDS row stride in halfs (128 + 8 pad)

typedef _Float16 half8 __attribute__((ext_vector_type(8)));
typedef float floatx4 __attribute__((ext_vector_type(4)));

// Per-bucket edge counts (bucket = dst >> 10).
__global__ __launch_bounds__(256) void hist_buckets(const int* __restrict__ dst, int E,
                                                    int* __restrict__ bucket_count) {
    __shared__ int h[NB_MAX];
    const int t = threadIdx.x;
    if (t < NB_MAX) h[t] = 0;
    __syncthreads();
    const int e0 = blockIdx.x * PART_CHUNK;
    #pragma unroll
    for (int q = 0; q < PART_VE; ++q) {
        const int e = e0 + q * 256 + t;
        if (e < E) atomicAdd(&h[dst[e] >> 10], 1);
    }
    __syncthreads();
    if (t < NB_MAX && h[t]) atomicAdd(&bucket_count[t], h[t]);
}

// Single-wave exclusive scan of the 128 bucket counts (lane owns 2 buckets).
__global__ __launch_bounds__(64) void scan_buckets(const int* __restrict__ bucket_count,
                                                   int* __restrict__ bucket_base,
                                                   int* __restrict__ bucket_cursor,
                                                   int* __restrict__ rowptr, int N, int E) {
    const int t = threadIdx.x;
    const int v0 = bucket_count[2 * t], v1 = bucket_count[2 * t + 1];
    const int tsum = v0 + v1;
    int inc = tsum;
    #pragma unroll
    for (int off = 1; off < 64; off <<= 1) {
        int u = __shfl_up(inc, off, 64);
        if (t >= off) inc += u;
    }
    const int excl = inc - tsum;
    bucket_base[2 * t] = excl;
    bucket_base[2 * t + 1] = excl + v0;
    bucket_cursor[2 * t] = excl;
    bucket_cursor[2 * t + 1] = excl + v0;
    if (t == 63) bucket_base[NB_MAX] = inc;   // == E
    if (t == 0) rowptr[N] = E;
}

// Partition edges into per-bucket contiguous regions with coalesced writes.
// Packed record: (d & 1023) << 17 | src.
__global__ __launch_bounds__(256) void partition_edges(
    const int* __restrict__ ei, int E,
    int* __restrict__ bucket_cursor, int* __restrict__ packed_out)
{
    __shared__ int stage[PART_CHUNK];
    __shared__ unsigned char bstage[PART_CHUNK];
    __shared__ int hist[NB_MAX], lbase[NB_MAX], gbase[NB_MAX], lcur[NB_MAX];
    const int t = threadIdx.x;
    const int e0 = blockIdx.x * PART_CHUNK;
    if (t < NB_MAX) hist[t] = 0;
    __syncthreads();

    int pk[PART_VE], bk[PART_VE];
    #pragma unroll
    for (int q = 0; q < PART_VE; ++q) {
        const int e = e0 + q * 256 + t;
        bk[q] = -1;
        if (e < E) {
            const int s = ei[e];
            const int d = ei[E + e];
            bk[q] = d >> 10;
            pk[q] = ((d & 1023) << 17) | s;
            atomicAdd(&hist[bk[q]], 1);
        }
    }
    __syncthreads();

    if (t < 64) {
        const int v0 = hist[2 * t], v1 = hist[2 * t + 1];
        const int tsum = v0 + v1;
        int inc = tsum;
        #pragma unroll
        for (int off = 1; off < 64; off <<= 1) {
            int u = __shfl_up(inc, off, 64);
            if (t >= off) inc += u;
        }
        const int excl = inc - tsum;
        lbase[2 * t] = excl;        lbase[2 * t + 1] = excl + v0;
        lcur[2 * t]  = excl;        lcur[2 * t + 1]  = excl + v0;
        gbase[2 * t]     = v0 ? atomicAdd(&bucket_cursor[2 * t], v0) : 0;
        gbase[2 * t + 1] = v1 ? atomicAdd(&bucket_cursor[2 * t + 1], v1) : 0;
    }
    __syncthreads();

    #pragma unroll
    for (int q = 0; q < PART_VE; ++q) {
        if (bk[q] >= 0) {
            const int p = atomicAdd(&lcur[bk[q]], 1);
            stage[p]  = pk[q];
            bstage[p] = (unsigned char)bk[q];
        }
    }
    __syncthreads();

    const int total = (E - e0 < PART_CHUNK) ? (E - e0) : PART_CHUNK;
    for (int i = t; i < total; i += 256) {
        const int b = bstage[i];
        packed_out[gbase[b] + (i - lbase[b])] = stage[i];
    }
}

// One block per 1024-node bucket: local histogram -> local scan -> rowptr/norm
// -> LDS-cursor scatter into this bucket's contiguous csr segment.
__global__ __launch_bounds__(1024) void build_csr(
    const int* __restrict__ packed, const int* __restrict__ bucket_base,
    int N, int* __restrict__ rowptr, float* __restrict__ normv,
    int* __restrict__ csr)
{
    __shared__ int ldeg[1024];
    __shared__ int lrow[1024];
    __shared__ int wtot[16];
    const int b = blockIdx.x;
    const int node0 = b << 10;
    const int t = threadIdx.x;
    const int jb = bucket_base[b], je = bucket_base[b + 1];

    ldeg[t] = 0;
    __syncthreads();
    for (int j = jb + t; j < je; j += 1024)
        atomicAdd(&ldeg[packed[j] >> 17], 1);
    __syncthreads();

    const int lane = t & 63, wid = t >> 6;
    const int v = ldeg[t];
    int inc = v;
    #pragma unroll
    for (int off = 1; off < 64; off <<= 1) {
        int u = __shfl_up(inc, off, 64);
        if (lane >= off) inc += u;
    }
    if (lane == 63) wtot[wid] = inc;
    __syncthreads();
    int woff = 0;
    for (int w = 0; w < wid; ++w) woff += wtot[w];
    const int excl = woff + inc - v;
    lrow[t] = excl;
    __syncthreads();

    const int nloc = (N - node0 < 1024) ? (N - node0) : 1024;
    if (t < nloc) {
        rowptr[node0 + t] = jb + excl;
        normv[node0 + t] = rsqrtf((float)(v + 1));   // +1 self-loop
    }
    __syncthreads();

    for (int j = jb + t; j < je; j += 1024) {
        const int pv = packed[j];
        const int slot = jb + atomicAdd(&lrow[pv >> 17], 1);
        csr[slot] = pv & 0x1FFFF;
    }
}

// Transpose-convert weights for MFMA B-operand: W1h[n][k] = (half)W1[k][n],
// W2h[n][k] = (half)W2[k][n]. 16384 + 8192 elems; one tiny kernel.
__global__ __launch_bounds__(256) void prep_weights(
    const float* __restrict__ W1, const float* __restrict__ W2,
    __half* __restrict__ W1h, __half* __restrict__ W2h)
{
    const int idx = blockIdx.x * 256 + threadIdx.x;
    if (idx < 128 * 128) {
        const int n = idx >> 7, k = idx & 127;
        W1h[idx] = __float2half(W1[k * 128 + n]);
    }
    const int idx2 = idx - 128 * 128;
    if (idx2 >= 0 && idx2 < 64 * 128) {
        const int n = idx2 >> 7, k = idx2 & 127;
        W2h[idx2] = __float2half(W2[k * 64 + n]);
    }
}

// Layer-1 MFMA GEMM: H'[row,0..127] = norm[row]*(x[row,:]@W1), fp16 out.
// Split-A (x = hi + lo) so only W-fp16 quantization enters the result.
// 256 thr = 4 waves; wave w owns rows w*16..+15, all 8 col-tiles.
__global__ __launch_bounds__(256) void gemm128_mfma(
    const float* __restrict__ A, const __half* __restrict__ Wh,  // [n][k]
    const float* __restrict__ norm, __half* __restrict__ Hout, int nrows)
{
    __shared__ _Float16 Ah[64 * LDA];
    __shared__ _Float16 Al[64 * LDA];
    __shared__ _Float16 Bh[128 * LDA];
    const int t = threadIdx.x;
    const int row0 = blockIdx.x * 64;

    {   // stage A split hi/lo: thread t -> row t>>2, 32-col segment (t&3)*32
        const int r = t >> 2;
        const int seg = (t & 3) * 32;
        int grow = row0 + r;
        if (grow > nrows - 1) grow = nrows - 1;
        const float* src = &A[(size_t)grow * K_DIM + seg];
        _Float16 hi[32], lo[32];
        #pragma unroll
        for (int i = 0; i < 8; ++i) {
            float4 v = *(const float4*)&src[i * 4];
            const float vf[4] = {v.x, v.y, v.z, v.w};
            #pragma unroll
            for (int j = 0; j < 4; ++j) {
                _Float16 h = (_Float16)vf[j];
                hi[i * 4 + j] = h;
                lo[i * 4 + j] = (_Float16)(vf[j] - (float)h);
            }
        }
        #pragma unroll
        for (int c = 0; c < 4; ++c) {
            *(half8*)&Ah[r * LDA + seg + c * 8] = *(half8*)&hi[c * 8];
            *(half8*)&Al[r * LDA + seg + c * 8] = *(half8*)&lo[c * 8];
        }
    }
    {   // stage B: 128x128 halfs = 2048 b128-chunks, 8 per thread
        const _Float16* wf = (const _Float16*)Wh;
        #pragma unroll
        for (int i = 0; i < 8; ++i) {
            const int id = i * 256 + t;
            const int n = id >> 4, kc = id & 15;
            *(half8*)&Bh[n * LDA + kc * 8] = *(const half8*)&wf[n * 128 + kc * 8];
        }
    }
    __syncthreads();

    const int lane = t & 63, wave = t >> 6;
    const int m = lane & 15, quad = lane >> 4;
    const int arow = wave * 16 + m;

    floatx4 acc[8];
    #pragma unroll
    for (int nt = 0; nt < 8; ++nt) acc[nt] = (floatx4){0.f, 0.f, 0.f, 0.f};

    #pragma unroll
    for (int k0 = 0; k0 < 128; k0 += 32) {
        half8 ah = *(const half8*)&Ah[arow * LDA + k0 + quad * 8];
        half8 al = *(const half8*)&Al[arow * LDA + k0 + quad * 8];
        #pragma unroll
        for (int nt = 0; nt < 8; ++nt) {
            half8 b = *(const half8*)&Bh[(nt * 16 + m) * LDA + k0 + quad * 8];
            acc[nt] = __builtin_amdgcn_mfma_f32_16x16x32_f16(ah, b, acc[nt], 0, 0, 0);
            acc[nt] = __builtin_amdgcn_mfma_f32_16x16x32_f16(al, b, acc[nt], 0, 0, 0);
        }
    }

    // D: row = quad*4 + reg, col = nt*16 + m
    #pragma unroll
    for (int reg = 0; reg < 4; ++reg) {
        const int row = row0 + wave * 16 + quad * 4 + reg;
        if (row < nrows) {
            const float nr = norm[row];
            #pragma unroll
            for (int nt = 0; nt < 8; ++nt)
                Hout[(size_t)row * 128 + nt * 16 + m] = __float2half(acc[nt][reg] * nr);
        }
    }
}

// Fused layer-1 aggregation + layer-2 GEMM, 512 threads = 8 waves,
// BARRIER-FREE after W2 staging. Wave w owns dst rows row0 + w*8 .. +7:
// gathers them (R11 inner loop) into its own LDS strip, then runs a
// wave-local MFMA over all 4 col-tiles. The A-fragment spans 16 rows
// (m = lane&15) but only the lower 8 are this wave's data; the upper 8 are
// the neighbor strip's bytes (possibly stale). Since D[r] depends only on
// A[r] for 16x16x32 MFMA, garbage stays in D rows 8..15, which are never
// stored. No inter-wave synchronization -> no straggler tax, MFMA of one
// wave overlaps gathers of others. LDS 37 KB -> 4 blocks/CU, 32-wave ceiling.
__global__ __launch_bounds__(512, 8) void gather_relu_gemm64(
    const int* __restrict__ rowptr, const int* __restrict__ csr,
    const float* __restrict__ norm, const __half* __restrict__ h,
    const float* __restrict__ bias, const __half* __restrict__ W2h,
    __half* __restrict__ h2, int n)
{
    __shared__ _Float16 Ah[72 * LDA];   // 64 data rows + 8 pad (wave 7 A-read overrun)
    __shared__ _Float16 Bh[64 * LDA];
    const int t = threadIdx.x;
    const int lane = t & 63, wave = t >> 6;
    const int row0 = blockIdx.x * 64;
    const __half2* hp = (const __half2*)h;   // row stride 64 half2 (256 B)

    {   // stage W2 [64][128] halfs = 1024 b128-chunks, 2 per thread
        const _Float16* wf = (const _Float16*)W2h;
        #pragma unroll
        for (int i = 0; i < 2; ++i) {
            const int id = i * 512 + t;
            const int nn = id >> 4, kc = id & 15;
            *(half8*)&Bh[nn * LDA + kc * 8] = *(const half8*)&wf[nn * 128 + kc * 8];
        }
    }
    __syncthreads();   // only barrier: Bh ready for all waves

    const float bx = bias[2 * lane], by = bias[2 * lane + 1];

    for (int i = 0; i < 8; ++i) {
        const int dl = (wave << 3) + i;
        const int d = __builtin_amdgcn_readfirstlane(row0 + dl);
        float ox = 0.f, oy = 0.f;
        if (d < n) {
            const int jb = rowptr[d], je = rowptr[d + 1];
            float ax[8] = {}, ay[8] = {};
            int j = jb;
            if (j + 8 <= je) {
                int s[8];
                #pragma unroll
                for (int q = 0; q < 8; ++q) s[q] = csr[j + q];
                for (; j + 16 <= je; j += 8) {
                    int sn[8];
                    #pragma unroll
                    for (int q = 0; q < 8; ++q) sn[q] = csr[j + 8 + q];
                    #pragma unroll
                    for (int q = 0; q < 8; ++q) {
                        const float2 v = __half22float2(hp[(size_t)s[q] * 64 + lane]);
                        ax[q] += v.x; ay[q] += v.y;
                    }
                    #pragma unroll
                    for (int q = 0; q < 8; ++q) s[q] = sn[q];
                }
                #pragma unroll
                for (int q = 0; q < 8; ++q) {
                    const float2 v = __half22float2(hp[(size_t)s[q] * 64 + lane]);
                    ax[q] += v.x; ay[q] += v.y;
                }
                j += 8;
            }
            for (; j < je; ++j) {
                const float2 v = __half22float2(hp[(size_t)csr[j] * 64 + lane]);
                ax[0] += v.x; ay[0] += v.y;
            }

            const float2 sv = __half22float2(hp[(size_t)d * 64 + lane]);  // self (premult)
            const float nd = norm[d];
            float sx = ((ax[0] + ax[1]) + (ax[2] + ax[3])) + ((ax[4] + ax[5]) + (ax[6] + ax[7])) + sv.x;
            float sy = ((ay[0] + ay[1]) + (ay[2] + ay[3])) + ((ay[4] + ay[5]) + (ay[6] + ay[7])) + sv.y;
            ox = fmaxf(fmaf(nd, sx, bx), 0.f);
            oy = fmaxf(fmaf(nd, sy, by), 0.f);
        }
        ((__half2*)Ah)[dl * (LDA / 2) + lane] = __floats2half2_rn(ox, oy);
    }

    // Wave-local gemm: D rows 0..7 valid (this wave's strip), 8..15 garbage.
    const int m = lane & 15, quad = lane >> 4;
    const int arow = (wave << 3) + m;          // m >= 8 reads neighbor strip (discarded)

    floatx4 acc[4];
    #pragma unroll
    for (int nt = 0; nt < 4; ++nt) acc[nt] = (floatx4){0.f, 0.f, 0.f, 0.f};

    #pragma unroll
    for (int k0 = 0; k0 < 128; k0 += 32) {
        half8 ah = *(const half8*)&Ah[arow * LDA + k0 + quad * 8];
        #pragma unroll
        for (int nt = 0; nt < 4; ++nt) {
            half8 b = *(const half8*)&Bh[(nt * 16 + m) * LDA + k0 + quad * 8];
            acc[nt] = __builtin_amdgcn_mfma_f32_16x16x32_f16(ah, b, acc[nt], 0, 0, 0);
        }
    }

    // D: row = quad*4 + reg (keep < 8), col = nt*16 + m
    #pragma unroll
    for (int reg = 0; reg < 4; ++reg) {
        const int rl = quad * 4 + reg;
        const int row = row0 + (wave << 3) + rl;
        if (rl < 8 && row < n) {
            const float nr = norm[row];
            #pragma unroll
            for (int nt = 0; nt < 4; ++nt)
                h2[(size_t)row * 64 + nt * 16 + m] = __float2half(acc[nt][reg] * nr);
        }
    }
}

// Layer-2 aggregation + row softmax (scalar-path); h' fp16, 64 cols = 64 lanes.
__global__ __launch_bounds__(256) void gather_softmax(
    const int* __restrict__ rowptr, const int* __restrict__ csr,
    const float* __restrict__ norm, const __half* __restrict__ h,
    const float* __restrict__ bias, float* __restrict__ out, int n)
{
    const int lane = threadIdx.x & 63;
    const int d = __builtin_amdgcn_readfirstlane(blockIdx.x * 4 + (threadIdx.x >> 6));
    if (d >= n) return;

    const int jb = rowptr[d], je = rowptr[d + 1];
    float acc[8] = {};
    int j = jb;
    if (j + 8 <= je) {
        int s[8];
        #pragma unroll
        for (int q = 0; q < 8; ++q) s[q] = csr[j + q];
        for (; j + 16 <= je; j += 8) {
            int sn[8];
            #pragma unroll
            for (int q = 0; q < 8; ++q) sn[q] = csr[j + 8 + q];
            #pragma unroll
            for (int q = 0; q < 8; ++q)
                acc[q] += __half2float(h[(size_t)s[q] * 64 + lane]);
            #pragma unroll
            for (int q = 0; q < 8; ++q) s[q] = sn[q];
        }
        #pragma unroll
        for (int q = 0; q < 8; ++q)
            acc[q] += __half2float(h[(size_t)s[q] * 64 + lane]);
        j += 8;
    }
    for (; j < je; ++j)
        acc[0] += __half2float(h[(size_t)csr[j] * 64 + lane]);

    const float nd = norm[d];
    float tot = ((acc[0] + acc[1]) + (acc[2] + acc[3])) +
                ((acc[4] + acc[5]) + (acc[6] + acc[7])) +
                __half2float(h[(size_t)d * 64 + lane]);
    float a = fmaf(nd, tot, bias[lane]);
    float m = a;
    #pragma unroll
    for (int off = 32; off; off >>= 1) m = fmaxf(m, __shfl_xor(m, off, 64));
    float ex = expf(a - m);
    float ssum = ex;
    #pragma unroll
    for (int off = 32; off; off >>= 1) ssum += __shfl_xor(ssum, off, 64);
    out[(size_t)d * 64 + lane] = ex / ssum;
}

extern "C" void kernel_launch(void* const* d_in, const int* in_sizes, int n_in,
                              void* d_out, int out_size, void* d_ws, size_t ws_size,
                              hipStream_t stream) {
    const float* x  = (const float*)d_in[0];
    const int*   ei = (const int*)d_in[1];
    const float* W1 = (const float*)d_in[2];
    const float* b1 = (const float*)d_in[3];
    const float* W2 = (const float*)d_in[4];
    const float* b2 = (const float*)d_in[5];
    float* out = (float*)d_out;

    const int N = in_sizes[0] / K_DIM;     // 100000 (<= 2^17 required)
    const int E = in_sizes[1] / 2;         // 1600000
    const int NBUCK = (N + 1023) >> 10;    // 98 buckets of 1024 nodes

    // Workspace layout (peak ~65 MB)
    size_t o = 0;
    char* base = (char*)d_ws;
    auto alloc = [&](size_t elems) {       // elems in 4-byte units
        void* p = base + o;
        o += (elems * 4 + 1023) & ~(size_t)1023;
        return p;
    };
    int*    bcount = (int*)   alloc(NB_MAX);
    int*    bbase  = (int*)   alloc(NB_MAX + 1);
    int*    bcur   = (int*)   alloc(NB_MAX);
    int*    rowptr = (int*)   alloc(N + 1);
    float*  norm   = (float*) alloc(N);
    int*    packed = (int*)   alloc(E);
    int*    csr    = (int*)   alloc(E);
    __half* W1h    = (__half*)alloc(128 * 128 / 2);
    __half* W2h    = (__half*)alloc(64 * 128 / 2);
    __half* h1h    = (__half*)alloc((size_t)N * 64);  // fp16 [Nx128]
    __half* h2h    = (__half*)alloc((size_t)N * 32);  // fp16 [Nx64]

    const int nb_c = (E + PART_CHUNK - 1) / PART_CHUNK;   // partition chunks
    const int nb_g = (N + 3) / 4;
    const int nb_m = (N + 63) / 64;

    // ---- CSR build (two-level partition) + weight prep ----
    hipMemsetAsync(bcount, 0, NB_MAX * sizeof(int), stream);
    prep_weights<<<96, 256, 0, stream>>>(W1, W2, W1h, W2h);
    hist_buckets<<<nb_c, 256, 0, stream>>>(ei + E, E, bcount);
    scan_buckets<<<1, 64, 0, stream>>>(bcount, bbase, bcur, rowptr, N, E);
    partition_edges<<<nb_c, 256, 0, stream>>>(ei, E, bcur, packed);
    build_csr<<<NBUCK, 1024, 0, stream>>>(packed, bbase, N, rowptr, norm, csr);

    // ---- Layer 1: h1' = norm .* (x@W1), fp16 [N x 128], MFMA split-A ----
    gemm128_mfma<<<nb_m, 256, 0, stream>>>(x, W1h, norm, h1h, N);

    // ---- Fused: agg1 = relu(gather(h1')) in LDS; h2' = norm .* (agg1@W2) ----
    gather_relu_gemm64<<<nb_m, 512, 0, stream>>>(rowptr, csr, norm, h1h, b1, W2h, h2h, N);

    // ---- Layer 2 aggregation + softmax ----
    gather_softmax<<<nb_g, 256, 0, stream>>>(rowptr, csr, norm, h2h, b2, out, N);
}

// Round 10
// 289.551 us; speedup vs baseline: 1.1691x; 1.0229x over previous
//
#include <hip/hip_runtime.h>
#include <hip/hip_bf16.h>
#include <hip/hip_fp16.h>

// GCN: out = softmax( GCNConv2( relu( GCNConv1(x) ) ) )
// GCNConv(x) = D^-1/2 (A+I) D^-1/2 (x W) + b
//
// Round 17 (3rd resubmit; R8/R9 benches were GPU-broker timeouts, no data):
//  (a) REVERT the R16 persistent/dynamic fused kernel (post-timing divergence
//      — suspected undef-propagation through the uninitialized-lane __shfl
//      broadcast of the atomic chunk id). Fused gather+gemm64 restored to the
//      R15 known-good static-grid form (passed, 69.6 us).
//  (b) gather_softmax: TWO DSTS PER WAVE. Old form used scalar 2 B fp16 loads
//      (128 B/wave-instr, 8-deep = 1 KB in flight). New form: half-wave hw
//      owns dst 2p+hw; 32 lanes x half2 cover the 128 B row, one instruction
//      covers both half-waves' rows = 256 B/instr, 8-deep = 2 KB in flight
//      (R11-proven MLP level; R12/R13 showed BW tracks bytes-in-flight).
//      Softmax reduction via __shfl_xor offsets <=16 (within 32-lane half);
//      output as coalesced float2.
// Requires N <= 2^17. N = 100000 here.

#define K_DIM 128
#define PART_VE 16
#define PART_CHUNK 4096   // 256 threads * 16 edges
#define NB_MAX 128        // bucket array size (N <= 128*1024)
#define LDA 136           // LDS row stride in halfs (128 + 8 pad)

typedef _Float16 half8 __attribute__((ext_vector_type(8)));
typedef float floatx4 __attribute__((ext_vector_type(4)));

// Per-bucket edge counts (bucket = dst >> 10).
__global__ __launch_bounds__(256) void hist_buckets(const int* __restrict__ dst, int E,
                                                    int* __restrict__ bucket_count) {
    __shared__ int h[NB_MAX];
    const int t = threadIdx.x;
    if (t < NB_MAX) h[t] = 0;
    __syncthreads();
    const int e0 = blockIdx.x * PART_CHUNK;
    #pragma unroll
    for (int q = 0; q < PART_VE; ++q) {
        const int e = e0 + q * 256 + t;
        if (e < E) atomicAdd(&h[dst[e] >> 10], 1);
    }
    __syncthreads();
    if (t < NB_MAX && h[t]) atomicAdd(&bucket_count[t], h[t]);
}

// Single-wave exclusive scan of the 128 bucket counts (lane owns 2 buckets).
__global__ __launch_bounds__(64) void scan_buckets(const int* __restrict__ bucket_count,
                                                   int* __restrict__ bucket_base,
                                                   int* __restrict__ bucket_cursor,
                                                   int* __restrict__ rowptr, int N, int E) {
    const int t = threadIdx.x;
    const int v0 = bucket_count[2 * t], v1 = bucket_count[2 * t + 1];
    const int tsum = v0 + v1;
    int inc = tsum;
    #pragma unroll
    for (int off = 1; off < 64; off <<= 1) {
        int u = __shfl_up(inc, off, 64);
        if (t >= off) inc += u;
    }
    const int excl = inc - tsum;
    bucket_base[2 * t] = excl;
    bucket_base[2 * t + 1] = excl + v0;
    bucket_cursor[2 * t] = excl;
    bucket_cursor[2 * t + 1] = excl + v0;
    if (t == 63) bucket_base[NB_MAX] = inc;   // == E
    if (t == 0) rowptr[N] = E;
}

// Partition edges into per-bucket contiguous regions with coalesced writes.
// Packed record: (d & 1023) << 17 | src.
__global__ __launch_bounds__(256) void partition_edges(
    const int* __restrict__ ei, int E,
    int* __restrict__ bucket_cursor, int* __restrict__ packed_out)
{
    __shared__ int stage[PART_CHUNK];
    __shared__ unsigned char bstage[PART_CHUNK];
    __shared__ int hist[NB_MAX], lbase[NB_MAX], gbase[NB_MAX], lcur[NB_MAX];
    const int t = threadIdx.x;
    const int e0 = blockIdx.x * PART_CHUNK;
    if (t < NB_MAX) hist[t] = 0;
    __syncthreads();

    int pk[PART_VE], bk[PART_VE];
    #pragma unroll
    for (int q = 0; q < PART_VE; ++q) {
        const int e = e0 + q * 256 + t;
        bk[q] = -1;
        if (e < E) {
            const int s = ei[e];
            const int d = ei[E + e];
            bk[q] = d >> 10;
            pk[q] = ((d & 1023) << 17) | s;
            atomicAdd(&hist[bk[q]], 1);
        }
    }
    __syncthreads();

    if (t < 64) {
        const int v0 = hist[2 * t], v1 = hist[2 * t + 1];
        const int tsum = v0 + v1;
        int inc = tsum;
        #pragma unroll
        for (int off = 1; off < 64; off <<= 1) {
            int u = __shfl_up(inc, off, 64);
            if (t >= off) inc += u;
        }
        const int excl = inc - tsum;
        lbase[2 * t] = excl;        lbase[2 * t + 1] = excl + v0;
        lcur[2 * t]  = excl;        lcur[2 * t + 1]  = excl + v0;
        gbase[2 * t]     = v0 ? atomicAdd(&bucket_cursor[2 * t], v0) : 0;
        gbase[2 * t + 1] = v1 ? atomicAdd(&bucket_cursor[2 * t + 1], v1) : 0;
    }
    __syncthreads();

    #pragma unroll
    for (int q = 0; q < PART_VE; ++q) {
        if (bk[q] >= 0) {
            const int p = atomicAdd(&lcur[bk[q]], 1);
            stage[p]  = pk[q];
            bstage[p] = (unsigned char)bk[q];
        }
    }
    __syncthreads();

    const int total = (E - e0 < PART_CHUNK) ? (E - e0) : PART_CHUNK;
    for (int i = t; i < total; i += 256) {
        const int b = bstage[i];
        packed_out[gbase[b] + (i - lbase[b])] = stage[i];
    }
}

// One block per 1024-node bucket: local histogram -> local scan -> rowptr/norm
// -> LDS-cursor scatter into this bucket's contiguous csr segment.
__global__ __launch_bounds__(1024) void build_csr(
    const int* __restrict__ packed, const int* __restrict__ bucket_base,
    int N, int* __restrict__ rowptr, float* __restrict__ normv,
    int* __restrict__ csr)
{
    __shared__ int ldeg[1024];
    __shared__ int lrow[1024];
    __shared__ int wtot[16];
    const int b = blockIdx.x;
    const int node0 = b << 10;
    const int t = threadIdx.x;
    const int jb = bucket_base[b], je = bucket_base[b + 1];

    ldeg[t] = 0;
    __syncthreads();
    for (int j = jb + t; j < je; j += 1024)
        atomicAdd(&ldeg[packed[j] >> 17], 1);
    __syncthreads();

    const int lane = t & 63, wid = t >> 6;
    const int v = ldeg[t];
    int inc = v;
    #pragma unroll
    for (int off = 1; off < 64; off <<= 1) {
        int u = __shfl_up(inc, off, 64);
        if (lane >= off) inc += u;
    }
    if (lane == 63) wtot[wid] = inc;
    __syncthreads();
    int woff = 0;
    for (int w = 0; w < wid; ++w) woff += wtot[w];
    const int excl = woff + inc - v;
    lrow[t] = excl;
    __syncthreads();

    const int nloc = (N - node0 < 1024) ? (N - node0) : 1024;
    if (t < nloc) {
        rowptr[node0 + t] = jb + excl;
        normv[node0 + t] = rsqrtf((float)(v + 1));   // +1 self-loop
    }
    __syncthreads();

    for (int j = jb + t; j < je; j += 1024) {
        const int pv = packed[j];
        const int slot = jb + atomicAdd(&lrow[pv >> 17], 1);
        csr[slot] = pv & 0x1FFFF;
    }
}

// Transpose-convert weights for MFMA B-operand: W1h[n][k] = (half)W1[k][n],
// W2h[n][k] = (half)W2[k][n]. 16384 + 8192 elems; one tiny kernel.
__global__ __launch_bounds__(256) void prep_weights(
    const float* __restrict__ W1, const float* __restrict__ W2,
    __half* __restrict__ W1h, __half* __restrict__ W2h)
{
    const int idx = blockIdx.x * 256 + threadIdx.x;
    if (idx < 128 * 128) {
        const int n = idx >> 7, k = idx & 127;
        W1h[idx] = __float2half(W1[k * 128 + n]);
    }
    const int idx2 = idx - 128 * 128;
    if (idx2 >= 0 && idx2 < 64 * 128) {
        const int n = idx2 >> 7, k = idx2 & 127;
        W2h[idx2] = __float2half(W2[k * 64 + n]);
    }
}

// Layer-1 MFMA GEMM: H'[row,0..127] = norm[row]*(x[row,:]@W1), fp16 out.
// Split-A (x = hi + lo) so only W-fp16 quantization enters the result.
// 256 thr = 4 waves; wave w owns rows w*16..+15, all 8 col-tiles.
__global__ __launch_bounds__(256) void gemm128_mfma(
    const float* __restrict__ A, const __half* __restrict__ Wh,  // [n][k]
    const float* __restrict__ norm, __half* __restrict__ Hout, int nrows)
{
    __shared__ _Float16 Ah[64 * LDA];
    __shared__ _Float16 Al[64 * LDA];
    __shared__ _Float16 Bh[128 * LDA];
    const int t = threadIdx.x;
    const int row0 = blockIdx.x * 64;

    {   // stage A split hi/lo: thread t -> row t>>2, 32-col segment (t&3)*32
        const int r = t >> 2;
        const int seg = (t & 3) * 32;
        int grow = row0 + r;
        if (grow > nrows - 1) grow = nrows - 1;
        const float* src = &A[(size_t)grow * K_DIM + seg];
        _Float16 hi[32], lo[32];
        #pragma unroll
        for (int i = 0; i < 8; ++i) {
            float4 v = *(const float4*)&src[i * 4];
            const float vf[4] = {v.x, v.y, v.z, v.w};
            #pragma unroll
            for (int j = 0; j < 4; ++j) {
                _Float16 h = (_Float16)vf[j];
                hi[i * 4 + j] = h;
                lo[i * 4 + j] = (_Float16)(vf[j] - (float)h);
            }
        }
        #pragma unroll
        for (int c = 0; c < 4; ++c) {
            *(half8*)&Ah[r * LDA + seg + c * 8] = *(half8*)&hi[c * 8];
            *(half8*)&Al[r * LDA + seg + c * 8] = *(half8*)&lo[c * 8];
        }
    }
    {   // stage B: 128x128 halfs = 2048 b128-chunks, 8 per thread
        const _Float16* wf = (const _Float16*)Wh;
        #pragma unroll
        for (int i = 0; i < 8; ++i) {
            const int id = i * 256 + t;
            const int n = id >> 4, kc = id & 15;
            *(half8*)&Bh[n * LDA + kc * 8] = *(const half8*)&wf[n * 128 + kc * 8];
        }
    }
    __syncthreads();

    const int lane = t & 63, wave = t >> 6;
    const int m = lane & 15, quad = lane >> 4;
    const int arow = wave * 16 + m;

    floatx4 acc[8];
    #pragma unroll
    for (int nt = 0; nt < 8; ++nt) acc[nt] = (floatx4){0.f, 0.f, 0.f, 0.f};

    #pragma unroll
    for (int k0 = 0; k0 < 128; k0 += 32) {
        half8 ah = *(const half8*)&Ah[arow * LDA + k0 + quad * 8];
        half8 al = *(const half8*)&Al[arow * LDA + k0 + quad * 8];
        #pragma unroll
        for (int nt = 0; nt < 8; ++nt) {
            half8 b = *(const half8*)&Bh[(nt * 16 + m) * LDA + k0 + quad * 8];
            acc[nt] = __builtin_amdgcn_mfma_f32_16x16x32_f16(ah, b, acc[nt], 0, 0, 0);
            acc[nt] = __builtin_amdgcn_mfma_f32_16x16x32_f16(al, b, acc[nt], 0, 0, 0);
        }
    }

    // D: row = quad*4 + reg, col = nt*16 + m
    #pragma unroll
    for (int reg = 0; reg < 4; ++reg) {
        const int row = row0 + wave * 16 + quad * 4 + reg;
        if (row < nrows) {
            const float nr = norm[row];
            #pragma unroll
            for (int nt = 0; nt < 8; ++nt)
                Hout[(size_t)row * 128 + nt * 16 + m] = __float2half(acc[nt][reg] * nr);
        }
    }
}

// Fused layer-1 aggregation + layer-2 GEMM, 512 threads = 8 waves,
// BARRIER-FREE after W2 staging (R15 known-good). Wave w owns dst rows
// row0 + w*8 .. +7: gathers them (R11 inner loop) into its own LDS strip,
// then runs a wave-local MFMA over all 4 col-tiles. A rows 8..15 are the
// neighbor strip's bytes (garbage); D row r depends only on A row r, so
// garbage stays in D rows 8..15, which are never stored.
__global__ __launch_bounds__(512, 8) void gather_relu_gemm64(
    const int* __restrict__ rowptr, const int* __restrict__ csr,
    const float* __restrict__ norm, const __half* __restrict__ h,
    const float* __restrict__ bias, const __half* __restrict__ W2h,
    __half* __restrict__ h2, int n)
{
    __shared__ _Float16 Ah[72 * LDA];   // 64 data rows + 8 pad (wave 7 A-read overrun)
    __shared__ _Float16 Bh[64 * LDA];
    const int t = threadIdx.x;
    const int lane = t & 63, wave = t >> 6;
    const int row0 = blockIdx.x * 64;
    const __half2* hp = (const __half2*)h;   // row stride 64 half2 (256 B)

    {   // stage W2 [64][128] halfs = 1024 b128-chunks, 2 per thread
        const _Float16* wf = (const _Float16*)W2h;
        #pragma unroll
        for (int i = 0; i < 2; ++i) {
            const int id = i * 512 + t;
            const int nn = id >> 4, kc = id & 15;
            *(half8*)&Bh[nn * LDA + kc * 8] = *(const half8*)&wf[nn * 128 + kc * 8];
        }
    }
    __syncthreads();   // only barrier: Bh ready for all waves

    const float bx = bias[2 * lane], by = bias[2 * lane + 1];

    for (int i = 0; i < 8; ++i) {
        const int dl = (wave << 3) + i;
        const int d = __builtin_amdgcn_readfirstlane(row0 + dl);
        float ox = 0.f, oy = 0.f;
        if (d < n) {
            const int jb = rowptr[d], je = rowptr[d + 1];
            float ax[8] = {}, ay[8] = {};
            int j = jb;
            if (j + 8 <= je) {
                int s[8];
                #pragma unroll
                for (int q = 0; q < 8; ++q) s[q] = csr[j + q];
                for (; j + 16 <= je; j += 8) {
                    int sn[8];
                    #pragma unroll
                    for (int q = 0; q < 8; ++q) sn[q] = csr[j + 8 + q];
                    #pragma unroll
                    for (int q = 0; q < 8; ++q) {
                        const float2 v = __half22float2(hp[(size_t)s[q] * 64 + lane]);
                        ax[q] += v.x; ay[q] += v.y;
                    }
                    #pragma unroll
                    for (int q = 0; q < 8; ++q) s[q] = sn[q];
                }
                #pragma unroll
                for (int q = 0; q < 8; ++q) {
                    const float2 v = __half22float2(hp[(size_t)s[q] * 64 + lane]);
                    ax[q] += v.x; ay[q] += v.y;
                }
                j += 8;
            }
            for (; j < je; ++j) {
                const float2 v = __half22float2(hp[(size_t)csr[j] * 64 + lane]);
                ax[0] += v.x; ay[0] += v.y;
            }

            const float2 sv = __half22float2(hp[(size_t)d * 64 + lane]);  // self (premult)
            const float nd = norm[d];
            float sx = ((ax[0] + ax[1]) + (ax[2] + ax[3])) + ((ax[4] + ax[5]) + (ax[6] + ax[7])) + sv.x;
            float sy = ((ay[0] + ay[1]) + (ay[2] + ay[3])) + ((ay[4] + ay[5]) + (ay[6] + ay[7])) + sv.y;
            ox = fmaxf(fmaf(nd, sx, bx), 0.f);
            oy = fmaxf(fmaf(nd, sy, by), 0.f);
        }
        ((__half2*)Ah)[dl * (LDA / 2) + lane] = __floats2half2_rn(ox, oy);
    }

    // Wave-local gemm: D rows 0..7 valid (this wave's strip), 8..15 garbage.
    const int m = lane & 15, quad = lane >> 4;
    const int arow = (wave << 3) + m;          // m >= 8 reads neighbor strip (discarded)

    floatx4 acc[4];
    #pragma unroll
    for (int nt = 0; nt < 4; ++nt) acc[nt] = (floatx4){0.f, 0.f, 0.f, 0.f};

    #pragma unroll
    for (int k0 = 0; k0 < 128; k0 += 32) {
        half8 ah = *(const half8*)&Ah[arow * LDA + k0 + quad * 8];
        #pragma unroll
        for (int nt = 0; nt < 4; ++nt) {
            half8 b = *(const half8*)&Bh[(nt * 16 + m) * LDA + k0 + quad * 8];
            acc[nt] = __builtin_amdgcn_mfma_f32_16x16x32_f16(ah, b, acc[nt], 0, 0, 0);
        }
    }

    // D: row = quad*4 + reg (keep < 8), col = nt*16 + m
    #pragma unroll
    for (int reg = 0; reg < 4; ++reg) {
        const int rl = quad * 4 + reg;
        const int row = row0 + (wave << 3) + rl;
        if (rl < 8 && row < n) {
            const float nr = norm[row];
            #pragma unroll
            for (int nt = 0; nt < 4; ++nt)
                h2[(size_t)row * 64 + nt * 16 + m] = __float2half(acc[nt][reg] * nr);
        }
    }
}

// Layer-2 aggregation + row softmax, TWO DSTS PER WAVE: half-wave hw owns
// dst 2p+hw; its 32 lanes read the 128 B h2 row as half2 (one wave-instr
// covers both half-waves' rows = 256 B, 8-deep = 2 KB in flight vs 1 KB for
// the old scalar-fp16 form). Reductions via __shfl_xor offsets <=16 stay
// within each 32-lane half. Output: coalesced float2 (256 B per dst).
__global__ __launch_bounds__(256) void gather_softmax(
    const int* __restrict__ rowptr, const int* __restrict__ csr,
    const float* __restrict__ norm, const __half* __restrict__ h,
    const float* __restrict__ bias, float* __restrict__ out, int n)
{
    const int t = threadIdx.x;
    const int lane = t & 63;
    const int cl = lane & 31;                               // half2 col 0..31
    const int d = blockIdx.x * 8 + ((t >> 6) << 1) + (lane >> 5);
    if (d >= n) return;
    const __half2* hp = (const __half2*)h;                  // row stride 32 half2 (128 B)

    const int jb = rowptr[d], je = rowptr[d + 1];
    float ax[8] = {}, ay[8] = {};
    int j = jb;
    if (j + 8 <= je) {
        int s[8];
        #pragma unroll
        for (int q = 0; q < 8; ++q) s[q] = csr[j + q];
        for (; j + 16 <= je; j += 8) {
            int sn[8];
            #pragma unroll
            for (int q = 0; q < 8; ++q) sn[q] = csr[j + 8 + q];
            #pragma unroll
            for (int q = 0; q < 8; ++q) {
                const float2 v = __half22float2(hp[(size_t)s[q] * 32 + cl]);
                ax[q] += v.x; ay[q] += v.y;
            }
            #pragma unroll
            for (int q = 0; q < 8; ++q) s[q] = sn[q];
        }
        #pragma unroll
        for (int q = 0; q < 8; ++q) {
            const float2 v = __half22float2(hp[(size_t)s[q] * 32 + cl]);
            ax[q] += v.x; ay[q] += v.y;
        }
        j += 8;
    }
    for (; j < je; ++j) {
        const float2 v = __half22float2(hp[(size_t)csr[j] * 32 + cl]);
        ax[0] += v.x; ay[0] += v.y;
    }

    const float2 sv = __half22float2(hp[(size_t)d * 32 + cl]);   // self (premult)
    const float nd = norm[d];
    float sx = ((ax[0] + ax[1]) + (ax[2] + ax[3])) + ((ax[4] + ax[5]) + (ax[6] + ax[7])) + sv.x;
    float sy = ((ay[0] + ay[1]) + (ay[2] + ay[3])) + ((ay[4] + ay[5]) + (ay[6] + ay[7])) + sv.y;
    const float a_x = fmaf(nd, sx, bias[2 * cl]);
    const float a_y = fmaf(nd, sy, bias[2 * cl + 1]);

    float m = fmaxf(a_x, a_y);
    #pragma unroll
    for (int off = 16; off; off >>= 1) m = fmaxf(m, __shfl_xor(m, off, 64));
    const float ex = expf(a_x - m), ey = expf(a_y - m);
    float ss = ex + ey;
    #pragma unroll
    for (int off = 16; off; off >>= 1) ss += __shfl_xor(ss, off, 64);
    const float inv = 1.f / ss;
    float2 o2; o2.x = ex * inv; o2.y = ey * inv;
    *(float2*)&out[(size_t)d * 64 + 2 * cl] = o2;
}

extern "C" void kernel_launch(void* const* d_in, const int* in_sizes, int n_in,
                              void* d_out, int out_size, void* d_ws, size_t ws_size,
                              hipStream_t stream) {
    const float* x  = (const float*)d_in[0];
    const int*   ei = (const int*)d_in[1];
    const float* W1 = (const float*)d_in[2];
    const float* b1 = (const float*)d_in[3];
    const float* W2 = (const float*)d_in[4];
    const float* b2 = (const float*)d_in[5];
    float* out = (float*)d_out;

    const int N = in_sizes[0] / K_DIM;     // 100000 (<= 2^17 required)
    const int E = in_sizes[1] / 2;         // 1600000
    const int NBUCK = (N + 1023) >> 10;    // 98 buckets of 1024 nodes

    // Workspace layout (peak ~65 MB)
    size_t o = 0;
    char* base = (char*)d_ws;
    auto alloc = [&](size_t elems) {       // elems in 4-byte units
        void* p = base + o;
        o += (elems * 4 + 1023) & ~(size_t)1023;
        return p;
    };
    int*    bcount = (int*)   alloc(NB_MAX);
    int*    bbase  = (int*)   alloc(NB_MAX + 1);
    int*    bcur   = (int*)   alloc(NB_MAX);
    int*    rowptr = (int*)   alloc(N + 1);
    float*  norm   = (float*) alloc(N);
    int*    packed = (int*)   alloc(E);
    int*    csr    = (int*)   alloc(E);
    __half* W1h    = (__half*)alloc(128 * 128 / 2);
    __half* W2h    = (__half*)alloc(64 * 128 / 2);
    __half* h1h    = (__half*)alloc((size_t)N * 64);  // fp16 [Nx128]
    __half* h2h    = (__half*)alloc((size_t)N * 32);  // fp16 [Nx64]

    const int nb_c = (E + PART_CHUNK - 1) / PART_CHUNK;   // partition chunks
    const int nb_g2 = (N + 7) / 8;                        // softmax: 8 dsts/block
    const int nb_m = (N + 63) / 64;

    // ---- CSR build (two-level partition) + weight prep ----
    hipMemsetAsync(bcount, 0, NB_MAX * sizeof(int), stream);
    prep_weights<<<96, 256, 0, stream>>>(W1, W2, W1h, W2h);
    hist_buckets<<<nb_c, 256, 0, stream>>>(ei + E, E, bcount);
    scan_buckets<<<1, 64, 0, stream>>>(bcount, bbase, bcur, rowptr, N, E);
    partition_edges<<<nb_c, 256, 0, stream>>>(ei, E, bcur, packed);
    build_csr<<<NBUCK, 1024, 0, stream>>>(packed, bbase, N, rowptr, norm, csr);

    // ---- Layer 1: h1' = norm .* (x@W1), fp16 [N x 128], MFMA split-A ----
    gemm128_mfma<<<nb_m, 256, 0, stream>>>(x, W1h, norm, h1h, N);

    // ---- Fused: agg1 = relu(gather(h1')) in LDS; h2' = norm .* (agg1@W2) ----
    gather_relu_gemm64<<<nb_m, 512, 0, stream>>>(rowptr, csr, norm, h1h, b1, W2h, h2h, N);

    // ---- Layer 2 aggregation + softmax ----
    gather_softmax<<<nb_g2, 256, 0, stream>>>(rowptr, csr, norm, h2h, b2, out, N);
}